// Round 1
// baseline (4327.098 us; speedup 1.0000x reference)
//
#include <hip/hip_runtime.h>
#include <cstdint>

// Problem constants (B,T,N,E)=(32,512,4,16), NI=16, EI=8, HN=HE=128, MH=256, C=8
constexpr int T_  = 512;
constexpr int HN_ = 128;

#define DEVI __device__ __forceinline__

DEVI float sigf(float x) { return 1.f / (1.f + __expf(-x)); }
DEVI float tanh_fast(float x) {
  x = fminf(fmaxf(x, -15.f), 15.f);
  float e = __expf(2.f * x);
  return (e - 1.f) / (e + 1.f);
}

// acc[n] += sum_k src[n*ld+k] * W[k*128 + d], K=128
template<int NR>
DEVI void layer128_acc(const float* __restrict__ src, int ld,
                       float* acc, const float* __restrict__ W, int d) {
  #pragma unroll 2
  for (int k4 = 0; k4 < 32; ++k4) {
    float4 w;
    w.x = W[(k4*4+0)*128 + d];
    w.y = W[(k4*4+1)*128 + d];
    w.z = W[(k4*4+2)*128 + d];
    w.w = W[(k4*4+3)*128 + d];
    #pragma unroll
    for (int n = 0; n < NR; ++n) {
      const float4 a = *reinterpret_cast<const float4*>(&src[n*ld + k4*4]);
      acc[n] = fmaf(a.x, w.x, acc[n]);
      acc[n] = fmaf(a.y, w.y, acc[n]);
      acc[n] = fmaf(a.z, w.z, acc[n]);
      acc[n] = fmaf(a.w, w.w, acc[n]);
    }
  }
}

// ---------------- K1: node MLP + 2 graph-conv layers -> xn [(b*4+n)][t][128]
__global__ __launch_bounds__(128) void node_mlp_kernel(
    const float* __restrict__ x_seq,
    const float* __restrict__ Wn1, const float* __restrict__ bn1,
    const float* __restrict__ Wn2, const float* __restrict__ bn2,
    const float* __restrict__ Wg1, const float* __restrict__ bg1,
    const float* __restrict__ Wg2, const float* __restrict__ bg2,
    float* __restrict__ xn)
{
  __shared__ __align__(16) float xs[4][16];
  __shared__ __align__(16) float A[4][128];
  __shared__ __align__(16) float Bb[4][128];
  const int bt = blockIdx.x;            // b*512 + t
  const int b  = bt >> 9, t = bt & 511;
  const int d  = threadIdx.x;

  if (d < 64) xs[d >> 4][d & 15] = x_seq[(size_t)bt * 64 + d];
  __syncthreads();

  float acc[4];
  // L1: 16 -> 128
  {
    const float bv = bn1[d];
    #pragma unroll
    for (int n = 0; n < 4; ++n) acc[n] = bv;
    #pragma unroll
    for (int k = 0; k < 16; ++k) {
      const float w = Wn1[k*128 + d];
      #pragma unroll
      for (int n = 0; n < 4; ++n) acc[n] = fmaf(xs[n][k], w, acc[n]);
    }
    #pragma unroll
    for (int n = 0; n < 4; ++n) A[n][d] = fmaxf(acc[n], 0.f);
  }
  __syncthreads();
  // L2: 128 -> 128
  {
    const float bv = bn2[d];
    #pragma unroll
    for (int n = 0; n < 4; ++n) acc[n] = bv;
    layer128_acc<4>(&A[0][0], 128, acc, Wn2, d);
    #pragma unroll
    for (int n = 0; n < 4; ++n) Bb[n][d] = fmaxf(acc[n], 0.f);
  }
  __syncthreads();
  // G1 matmul: y = Bb @ Wg1 -> A
  {
    #pragma unroll
    for (int n = 0; n < 4; ++n) acc[n] = 0.f;
    layer128_acc<4>(&Bb[0][0], 128, acc, Wg1, d);
    #pragma unroll
    for (int n = 0; n < 4; ++n) A[n][d] = acc[n];
  }
  __syncthreads();
  // adj mix + bias + relu -> Bb   (out_i = (sum_j y_j + y_i)/5)
  {
    const float y0 = A[0][d], y1 = A[1][d], y2 = A[2][d], y3 = A[3][d];
    const float s = y0 + y1 + y2 + y3;
    const float bv = bg1[d];
    Bb[0][d] = fmaxf((s + y0) * 0.2f + bv, 0.f);
    Bb[1][d] = fmaxf((s + y1) * 0.2f + bv, 0.f);
    Bb[2][d] = fmaxf((s + y2) * 0.2f + bv, 0.f);
    Bb[3][d] = fmaxf((s + y3) * 0.2f + bv, 0.f);
  }
  __syncthreads();
  // G2 matmul -> A
  {
    #pragma unroll
    for (int n = 0; n < 4; ++n) acc[n] = 0.f;
    layer128_acc<4>(&Bb[0][0], 128, acc, Wg2, d);
    #pragma unroll
    for (int n = 0; n < 4; ++n) A[n][d] = acc[n];
  }
  __syncthreads();
  // mix2 + bias + relu -> global, LSTM-friendly layout [(b*4+n)][t][d]
  {
    const float y0 = A[0][d], y1 = A[1][d], y2 = A[2][d], y3 = A[3][d];
    const float s = y0 + y1 + y2 + y3;
    const float bv = bg2[d];
    const float o0 = fmaxf((s + y0) * 0.2f + bv, 0.f);
    const float o1 = fmaxf((s + y1) * 0.2f + bv, 0.f);
    const float o2 = fmaxf((s + y2) * 0.2f + bv, 0.f);
    const float o3 = fmaxf((s + y3) * 0.2f + bv, 0.f);
    xn[((size_t)(b*4+0)*T_ + t)*HN_ + d] = o0;
    xn[((size_t)(b*4+1)*T_ + t)*HN_ + d] = o1;
    xn[((size_t)(b*4+2)*T_ + t)*HN_ + d] = o2;
    xn[((size_t)(b*4+3)*T_ + t)*HN_ + d] = o3;
  }
}

// ---------------- K2: edge MLP (4 layers) -> en [(b*16+e)][t][128]
__global__ __launch_bounds__(128) void edge_mlp_kernel(
    const float* __restrict__ ea,
    const float* __restrict__ We1, const float* __restrict__ be1,
    const float* __restrict__ We2, const float* __restrict__ be2,
    const float* __restrict__ Wef1, const float* __restrict__ bef1,
    const float* __restrict__ Wef2, const float* __restrict__ bef2,
    float* __restrict__ en)
{
  __shared__ __align__(16) float es[16][8];
  __shared__ __align__(16) float A[16][128];
  __shared__ __align__(16) float Bb[16][128];
  const int bt = blockIdx.x;
  const int b  = bt >> 9, t = bt & 511;
  const int d  = threadIdx.x;

  es[d >> 3][d & 7] = ea[(size_t)bt * 128 + d];
  __syncthreads();

  float acc[16];
  // L1: 8 -> 128
  {
    const float bv = be1[d];
    #pragma unroll
    for (int e = 0; e < 16; ++e) acc[e] = bv;
    #pragma unroll
    for (int k = 0; k < 8; ++k) {
      const float w = We1[k*128 + d];
      #pragma unroll
      for (int e = 0; e < 16; ++e) acc[e] = fmaf(es[e][k], w, acc[e]);
    }
    #pragma unroll
    for (int e = 0; e < 16; ++e) A[e][d] = fmaxf(acc[e], 0.f);
  }
  __syncthreads();
  // L2
  {
    const float bv = be2[d];
    #pragma unroll
    for (int e = 0; e < 16; ++e) acc[e] = bv;
    layer128_acc<16>(&A[0][0], 128, acc, We2, d);
    #pragma unroll
    for (int e = 0; e < 16; ++e) Bb[e][d] = fmaxf(acc[e], 0.f);
  }
  __syncthreads();
  // L3
  {
    const float bv = bef1[d];
    #pragma unroll
    for (int e = 0; e < 16; ++e) acc[e] = bv;
    layer128_acc<16>(&Bb[0][0], 128, acc, Wef1, d);
    #pragma unroll
    for (int e = 0; e < 16; ++e) A[e][d] = fmaxf(acc[e], 0.f);
  }
  __syncthreads();
  // L4 -> global
  {
    const float bv = bef2[d];
    #pragma unroll
    for (int e = 0; e < 16; ++e) acc[e] = bv;
    layer128_acc<16>(&A[0][0], 128, acc, Wef2, d);
    #pragma unroll
    for (int e = 0; e < 16; ++e)
      en[((size_t)(b*16+e)*T_ + t)*HN_ + d] = fmaxf(acc[e], 0.f);
  }
}

// ---------------- K3: LSTM, block-local recurrence, in-place x->h
// Thread j owns gate column j (Whh column in VGPRs). S sequences per block.
template<int S>
__global__ __launch_bounds__(512, 1) void lstm_kernel(
    const float* __restrict__ Wih, const float* __restrict__ Whh,
    const float* __restrict__ bias, float* __restrict__ xh)
{
  constexpr int H = 128, G = 512, CT = 16;
  __shared__ __align__(16) float h_lds[S][H];
  __shared__ __align__(16) float z_lds[S][G];
  __shared__ __align__(16) float x_lds[S][CT * H];
  __shared__ __align__(16) float xz_lds[S][CT][G];

  const int j = threadIdx.x;
  const int64_t seq0 = (int64_t)blockIdx.x * S;

  // Whh column j -> VGPRs (128 regs)
  float4 whh[32];
  #pragma unroll
  for (int k4 = 0; k4 < 32; ++k4) {
    whh[k4].x = Whh[(k4*4+0)*G + j];
    whh[k4].y = Whh[(k4*4+1)*G + j];
    whh[k4].z = Whh[(k4*4+2)*G + j];
    whh[k4].w = Whh[(k4*4+3)*G + j];
  }
  const float bj = bias[j];
  float c_reg = 0.f;
  if (j < S * H) h_lds[j >> 7][j & 127] = 0.f;
  __syncthreads();

  for (int t0 = 0; t0 < T_; t0 += CT) {
    // stage x chunk [S][CT][H]
    constexpr int TOT4 = S * CT * H / 4;
    #pragma unroll
    for (int u0 = 0; u0 < TOT4; u0 += 512) {
      const int u = u0 + j;
      const int flat = u * 4;
      const int s = flat / (CT * H);
      const int rem = flat - s * (CT * H);
      const float4 v = *reinterpret_cast<const float4*>(
          &xh[(seq0 + s) * (T_ * H) + t0 * H + rem]);
      *reinterpret_cast<float4*>(&x_lds[s][rem]) = v;
    }
    __syncthreads();

    // xz = b + x @ Wih for the chunk (Wih streamed once per chunk)
    float acc[S][CT];
    #pragma unroll
    for (int s = 0; s < S; ++s)
      #pragma unroll
      for (int c = 0; c < CT; ++c) acc[s][c] = bj;
    for (int k4 = 0; k4 < 32; ++k4) {
      float4 w;
      w.x = Wih[(k4*4+0)*G + j];
      w.y = Wih[(k4*4+1)*G + j];
      w.z = Wih[(k4*4+2)*G + j];
      w.w = Wih[(k4*4+3)*G + j];
      #pragma unroll
      for (int s = 0; s < S; ++s)
        #pragma unroll
        for (int c = 0; c < CT; ++c) {
          const float4 a = *reinterpret_cast<const float4*>(&x_lds[s][c*H + k4*4]);
          acc[s][c] = fmaf(a.x, w.x, acc[s][c]);
          acc[s][c] = fmaf(a.y, w.y, acc[s][c]);
          acc[s][c] = fmaf(a.z, w.z, acc[s][c]);
          acc[s][c] = fmaf(a.w, w.w, acc[s][c]);
        }
    }
    #pragma unroll
    for (int s = 0; s < S; ++s)
      #pragma unroll
      for (int c = 0; c < CT; ++c) xz_lds[s][c][j] = acc[s][c];
    // (xz_lds written and later read by the same thread -> no barrier needed)

    for (int ct = 0; ct < CT; ++ct) {
      #pragma unroll
      for (int s = 0; s < S; ++s) {
        float p0 = xz_lds[s][ct][j], p1 = 0.f, p2 = 0.f, p3 = 0.f;
        #pragma unroll
        for (int k4 = 0; k4 < 32; ++k4) {
          const float4 h4 = *reinterpret_cast<const float4*>(&h_lds[s][k4*4]);
          p0 = fmaf(h4.x, whh[k4].x, p0);
          p1 = fmaf(h4.y, whh[k4].y, p1);
          p2 = fmaf(h4.z, whh[k4].z, p2);
          p3 = fmaf(h4.w, whh[k4].w, p3);
        }
        z_lds[s][j] = (p0 + p1) + (p2 + p3);
      }
      __syncthreads();
      if (j < S * H) {
        const int s = j >> 7, d = j & 127;
        const float zi = z_lds[s][d];
        const float zf = z_lds[s][H + d];
        const float zg = z_lds[s][2*H + d];
        const float zo = z_lds[s][3*H + d];
        c_reg = sigf(zf) * c_reg + sigf(zi) * tanh_fast(zg);
        const float h = sigf(zo) * tanh_fast(c_reg);
        h_lds[s][d] = h;
        xh[(seq0 + s) * (T_ * H) + (int64_t)(t0 + ct) * H + d] = h;  // in-place
      }
      __syncthreads();
    }
  }
}

// ---------------- K4: gather + classifier (384 -> 256 -> 8)
__global__ __launch_bounds__(256) void classifier_kernel(
    const float* __restrict__ hn, const float* __restrict__ he,
    const float* __restrict__ Wc1, const float* __restrict__ bc1,
    const float* __restrict__ Wc2, const float* __restrict__ bc2,
    float* __restrict__ out)
{
  constexpr int HL = 132, HIDL = 260;   // padded strides (bank-conflict-free)
  __shared__ __align__(16) float hn_l[4][HL];
  __shared__ __align__(16) float he_l[16][HL];
  __shared__ __align__(16) float hid[16][HIDL];
  const int bt = blockIdx.x;
  const int b  = bt >> 9, t = bt & 511;
  const int j  = threadIdx.x;

  for (int idx = j; idx < 512; idx += 256) {
    const int n = idx >> 7, d = idx & 127;
    hn_l[n][d] = hn[((size_t)(b*4+n)*T_ + t)*HN_ + d];
  }
  for (int idx = j; idx < 2048; idx += 256) {
    const int e = idx >> 7, d = idx & 127;
    he_l[e][d] = he[((size_t)(b*16+e)*T_ + t)*HN_ + d];
  }
  __syncthreads();

  float acc[16];
  #pragma unroll
  for (int e = 0; e < 16; ++e) acc[e] = bc1[j];

  // segment A: src node features (src = e>>2), Wc1 rows [0,128)
  #pragma unroll 2
  for (int k4 = 0; k4 < 32; ++k4) {
    float4 w;
    w.x = Wc1[(k4*4+0)*256 + j];
    w.y = Wc1[(k4*4+1)*256 + j];
    w.z = Wc1[(k4*4+2)*256 + j];
    w.w = Wc1[(k4*4+3)*256 + j];
    float4 hv[4];
    #pragma unroll
    for (int n = 0; n < 4; ++n) hv[n] = *reinterpret_cast<const float4*>(&hn_l[n][k4*4]);
    #pragma unroll
    for (int e = 0; e < 16; ++e) {
      const float4 a = hv[e >> 2];
      acc[e] = fmaf(a.x, w.x, acc[e]);
      acc[e] = fmaf(a.y, w.y, acc[e]);
      acc[e] = fmaf(a.z, w.z, acc[e]);
      acc[e] = fmaf(a.w, w.w, acc[e]);
    }
  }
  // segment B: dst node features (dst = e&3), Wc1 rows [128,256)
  #pragma unroll 2
  for (int k4 = 0; k4 < 32; ++k4) {
    float4 w;
    w.x = Wc1[(128 + k4*4+0)*256 + j];
    w.y = Wc1[(128 + k4*4+1)*256 + j];
    w.z = Wc1[(128 + k4*4+2)*256 + j];
    w.w = Wc1[(128 + k4*4+3)*256 + j];
    float4 hv[4];
    #pragma unroll
    for (int n = 0; n < 4; ++n) hv[n] = *reinterpret_cast<const float4*>(&hn_l[n][k4*4]);
    #pragma unroll
    for (int e = 0; e < 16; ++e) {
      const float4 a = hv[e & 3];
      acc[e] = fmaf(a.x, w.x, acc[e]);
      acc[e] = fmaf(a.y, w.y, acc[e]);
      acc[e] = fmaf(a.z, w.z, acc[e]);
      acc[e] = fmaf(a.w, w.w, acc[e]);
    }
  }
  // segment C: edge features, Wc1 rows [256,384)
  #pragma unroll 2
  for (int k4 = 0; k4 < 32; ++k4) {
    float4 w;
    w.x = Wc1[(256 + k4*4+0)*256 + j];
    w.y = Wc1[(256 + k4*4+1)*256 + j];
    w.z = Wc1[(256 + k4*4+2)*256 + j];
    w.w = Wc1[(256 + k4*4+3)*256 + j];
    #pragma unroll
    for (int e = 0; e < 16; ++e) {
      const float4 a = *reinterpret_cast<const float4*>(&he_l[e][k4*4]);
      acc[e] = fmaf(a.x, w.x, acc[e]);
      acc[e] = fmaf(a.y, w.y, acc[e]);
      acc[e] = fmaf(a.z, w.z, acc[e]);
      acc[e] = fmaf(a.w, w.w, acc[e]);
    }
  }
  #pragma unroll
  for (int e = 0; e < 16; ++e) hid[e][j] = fmaxf(acc[e], 0.f);
  __syncthreads();

  if (j < 128) {
    const int e = j >> 3, c = j & 7;
    float p0 = bc2[c], p1 = 0.f, p2 = 0.f, p3 = 0.f;
    #pragma unroll 8
    for (int k4 = 0; k4 < 64; ++k4) {
      const float4 hq = *reinterpret_cast<const float4*>(&hid[e][k4*4]);
      p0 = fmaf(hq.x, Wc2[(k4*4+0)*8 + c], p0);
      p1 = fmaf(hq.y, Wc2[(k4*4+1)*8 + c], p1);
      p2 = fmaf(hq.z, Wc2[(k4*4+2)*8 + c], p2);
      p3 = fmaf(hq.w, Wc2[(k4*4+3)*8 + c], p3);
    }
    out[((size_t)bt * 16 + e) * 8 + c] = (p0 + p1) + (p2 + p3);
  }
}

extern "C" void kernel_launch(void* const* d_in, const int* in_sizes, int n_in,
                              void* d_out, int out_size, void* d_ws, size_t ws_size,
                              hipStream_t stream) {
  (void)in_sizes; (void)n_in; (void)out_size; (void)ws_size;
  const float* x_seq = (const float*)d_in[0];
  const float* ea    = (const float*)d_in[1];
  const float* Wn1 = (const float*)d_in[2];
  const float* bn1 = (const float*)d_in[3];
  const float* Wn2 = (const float*)d_in[4];
  const float* bn2 = (const float*)d_in[5];
  const float* We1 = (const float*)d_in[6];
  const float* be1 = (const float*)d_in[7];
  const float* We2 = (const float*)d_in[8];
  const float* be2 = (const float*)d_in[9];
  const float* Wg1 = (const float*)d_in[10];
  const float* bg1 = (const float*)d_in[11];
  const float* Wg2 = (const float*)d_in[12];
  const float* bg2 = (const float*)d_in[13];
  const float* Wef1 = (const float*)d_in[14];
  const float* bef1 = (const float*)d_in[15];
  const float* Wef2 = (const float*)d_in[16];
  const float* bef2 = (const float*)d_in[17];
  const float* Wih_n = (const float*)d_in[18];
  const float* Whh_n = (const float*)d_in[19];
  const float* b_n   = (const float*)d_in[20];
  const float* Wih_e = (const float*)d_in[21];
  const float* Whh_e = (const float*)d_in[22];
  const float* b_e   = (const float*)d_in[23];
  const float* Wc1 = (const float*)d_in[24];
  const float* bc1 = (const float*)d_in[25];
  const float* Wc2 = (const float*)d_in[26];
  const float* bc2 = (const float*)d_in[27];

  // workspace: xn/hn [128][512][128] f32 (33.5MB), en/he [512][512][128] f32 (134MB)
  float* xn = (float*)d_ws;
  float* en = xn + (size_t)128 * T_ * HN_;
  float* out = (float*)d_out;

  node_mlp_kernel<<<32*512, 128, 0, stream>>>(x_seq, Wn1, bn1, Wn2, bn2,
                                              Wg1, bg1, Wg2, bg2, xn);
  edge_mlp_kernel<<<32*512, 128, 0, stream>>>(ea, We1, be1, We2, be2,
                                              Wef1, bef1, Wef2, bef2, en);
  lstm_kernel<1><<<128, 512, 0, stream>>>(Wih_n, Whh_n, b_n, xn);  // 128 node seqs
  lstm_kernel<2><<<256, 512, 0, stream>>>(Wih_e, Whh_e, b_e, en);  // 512 edge seqs
  classifier_kernel<<<32*512, 256, 0, stream>>>(xn, en, Wc1, bc1, Wc2, bc2, out);
}

// Round 2
// 2190.079 us; speedup vs baseline: 1.9758x; 1.9758x over previous
//
#include <hip/hip_runtime.h>
#include <cstdint>

// Problem constants (B,T,N,E)=(32,512,4,16), NI=16, EI=8, HN=HE=128, MH=256, C=8
constexpr int T_  = 512;
constexpr int HN_ = 128;

#define DEVI __device__ __forceinline__

typedef __bf16 bf16x8 __attribute__((ext_vector_type(8)));
typedef __bf16 bf16x2 __attribute__((ext_vector_type(2)));
typedef float  f32x4  __attribute__((ext_vector_type(4)));

DEVI float sigf(float x) { return __builtin_amdgcn_rcpf(1.f + __expf(-x)); }
DEVI float tanh_fast(float x) {
  x = fminf(fmaxf(x, -15.f), 15.f);
  return 1.f - 2.f * __builtin_amdgcn_rcpf(1.f + __expf(2.f * x));
}

// acc[n] += sum_k src[n*ld+k] * W[k*128 + d], K=128
template<int NR>
DEVI void layer128_acc(const float* __restrict__ src, int ld,
                       float* acc, const float* __restrict__ W, int d) {
  #pragma unroll 2
  for (int k4 = 0; k4 < 32; ++k4) {
    float4 w;
    w.x = W[(k4*4+0)*128 + d];
    w.y = W[(k4*4+1)*128 + d];
    w.z = W[(k4*4+2)*128 + d];
    w.w = W[(k4*4+3)*128 + d];
    #pragma unroll
    for (int n = 0; n < NR; ++n) {
      const float4 a = *reinterpret_cast<const float4*>(&src[n*ld + k4*4]);
      acc[n] = fmaf(a.x, w.x, acc[n]);
      acc[n] = fmaf(a.y, w.y, acc[n]);
      acc[n] = fmaf(a.z, w.z, acc[n]);
      acc[n] = fmaf(a.w, w.w, acc[n]);
    }
  }
}

// ---------------- K1: node MLP + 2 graph-conv layers -> xn [(b*4+n)][t][128]
__global__ __launch_bounds__(128) void node_mlp_kernel(
    const float* __restrict__ x_seq,
    const float* __restrict__ Wn1, const float* __restrict__ bn1,
    const float* __restrict__ Wn2, const float* __restrict__ bn2,
    const float* __restrict__ Wg1, const float* __restrict__ bg1,
    const float* __restrict__ Wg2, const float* __restrict__ bg2,
    float* __restrict__ xn)
{
  __shared__ __align__(16) float xs[4][16];
  __shared__ __align__(16) float A[4][128];
  __shared__ __align__(16) float Bb[4][128];
  const int bt = blockIdx.x;            // b*512 + t
  const int b  = bt >> 9, t = bt & 511;
  const int d  = threadIdx.x;

  if (d < 64) xs[d >> 4][d & 15] = x_seq[(size_t)bt * 64 + d];
  __syncthreads();

  float acc[4];
  {
    const float bv = bn1[d];
    #pragma unroll
    for (int n = 0; n < 4; ++n) acc[n] = bv;
    #pragma unroll
    for (int k = 0; k < 16; ++k) {
      const float w = Wn1[k*128 + d];
      #pragma unroll
      for (int n = 0; n < 4; ++n) acc[n] = fmaf(xs[n][k], w, acc[n]);
    }
    #pragma unroll
    for (int n = 0; n < 4; ++n) A[n][d] = fmaxf(acc[n], 0.f);
  }
  __syncthreads();
  {
    const float bv = bn2[d];
    #pragma unroll
    for (int n = 0; n < 4; ++n) acc[n] = bv;
    layer128_acc<4>(&A[0][0], 128, acc, Wn2, d);
    #pragma unroll
    for (int n = 0; n < 4; ++n) Bb[n][d] = fmaxf(acc[n], 0.f);
  }
  __syncthreads();
  {
    #pragma unroll
    for (int n = 0; n < 4; ++n) acc[n] = 0.f;
    layer128_acc<4>(&Bb[0][0], 128, acc, Wg1, d);
    #pragma unroll
    for (int n = 0; n < 4; ++n) A[n][d] = acc[n];
  }
  __syncthreads();
  {
    const float y0 = A[0][d], y1 = A[1][d], y2 = A[2][d], y3 = A[3][d];
    const float s = y0 + y1 + y2 + y3;
    const float bv = bg1[d];
    Bb[0][d] = fmaxf((s + y0) * 0.2f + bv, 0.f);
    Bb[1][d] = fmaxf((s + y1) * 0.2f + bv, 0.f);
    Bb[2][d] = fmaxf((s + y2) * 0.2f + bv, 0.f);
    Bb[3][d] = fmaxf((s + y3) * 0.2f + bv, 0.f);
  }
  __syncthreads();
  {
    #pragma unroll
    for (int n = 0; n < 4; ++n) acc[n] = 0.f;
    layer128_acc<4>(&Bb[0][0], 128, acc, Wg2, d);
    #pragma unroll
    for (int n = 0; n < 4; ++n) A[n][d] = acc[n];
  }
  __syncthreads();
  {
    const float y0 = A[0][d], y1 = A[1][d], y2 = A[2][d], y3 = A[3][d];
    const float s = y0 + y1 + y2 + y3;
    const float bv = bg2[d];
    xn[((size_t)(b*4+0)*T_ + t)*HN_ + d] = fmaxf((s + y0) * 0.2f + bv, 0.f);
    xn[((size_t)(b*4+1)*T_ + t)*HN_ + d] = fmaxf((s + y1) * 0.2f + bv, 0.f);
    xn[((size_t)(b*4+2)*T_ + t)*HN_ + d] = fmaxf((s + y2) * 0.2f + bv, 0.f);
    xn[((size_t)(b*4+3)*T_ + t)*HN_ + d] = fmaxf((s + y3) * 0.2f + bv, 0.f);
  }
}

// ---------------- K2: edge MLP (4 layers) -> en [(b*16+e)][t][128]
__global__ __launch_bounds__(128) void edge_mlp_kernel(
    const float* __restrict__ ea,
    const float* __restrict__ We1, const float* __restrict__ be1,
    const float* __restrict__ We2, const float* __restrict__ be2,
    const float* __restrict__ Wef1, const float* __restrict__ bef1,
    const float* __restrict__ Wef2, const float* __restrict__ bef2,
    float* __restrict__ en)
{
  __shared__ __align__(16) float es[16][8];
  __shared__ __align__(16) float A[16][128];
  __shared__ __align__(16) float Bb[16][128];
  const int bt = blockIdx.x;
  const int b  = bt >> 9, t = bt & 511;
  const int d  = threadIdx.x;

  es[d >> 3][d & 7] = ea[(size_t)bt * 128 + d];
  __syncthreads();

  float acc[16];
  {
    const float bv = be1[d];
    #pragma unroll
    for (int e = 0; e < 16; ++e) acc[e] = bv;
    #pragma unroll
    for (int k = 0; k < 8; ++k) {
      const float w = We1[k*128 + d];
      #pragma unroll
      for (int e = 0; e < 16; ++e) acc[e] = fmaf(es[e][k], w, acc[e]);
    }
    #pragma unroll
    for (int e = 0; e < 16; ++e) A[e][d] = fmaxf(acc[e], 0.f);
  }
  __syncthreads();
  {
    const float bv = be2[d];
    #pragma unroll
    for (int e = 0; e < 16; ++e) acc[e] = bv;
    layer128_acc<16>(&A[0][0], 128, acc, We2, d);
    #pragma unroll
    for (int e = 0; e < 16; ++e) Bb[e][d] = fmaxf(acc[e], 0.f);
  }
  __syncthreads();
  {
    const float bv = bef1[d];
    #pragma unroll
    for (int e = 0; e < 16; ++e) acc[e] = bv;
    layer128_acc<16>(&Bb[0][0], 128, acc, Wef1, d);
    #pragma unroll
    for (int e = 0; e < 16; ++e) A[e][d] = fmaxf(acc[e], 0.f);
  }
  __syncthreads();
  {
    const float bv = bef2[d];
    #pragma unroll
    for (int e = 0; e < 16; ++e) acc[e] = bv;
    layer128_acc<16>(&A[0][0], 128, acc, Wef2, d);
    #pragma unroll
    for (int e = 0; e < 16; ++e)
      en[((size_t)(b*16+e)*T_ + t)*HN_ + d] = fmaxf(acc[e], 0.f);
  }
}

// ---------------- K3: fused MFMA LSTM (node blocks 0..15, edge blocks 16..79)
// 8 seqs/block (MFMA M=8 of 16, rows 8..15 zero-masked), 512 thr = 8 waves,
// wave w owns gate cols [64w, 64w+64): 4 N-tiles x 4 K-tiles of W in VGPRs.
// Per step: z = bias + x_t@Wih + h@Whh via 16x16x32 bf16 MFMA; gates in f32.
// h written f32 in-place over x (global) and bf16 to LDS for next step.
__global__ __launch_bounds__(512, 2) void lstm_mfma_kernel(
    const float* __restrict__ Wih_n, const float* __restrict__ Whh_n,
    const float* __restrict__ b_n,
    const float* __restrict__ Wih_e, const float* __restrict__ Whh_e,
    const float* __restrict__ b_e,
    float* __restrict__ xn, float* __restrict__ en)
{
  constexpr int XROW = 2064;  // bf16 elems per seq row of x chunk (16*128 + 16 pad)
  constexpr int HROW = 144;   // bf16 elems per h row (128 + 16 pad)
  constexpr int ZROW = 520;   // f32 elems per z row (512 + 8 pad)
  __shared__ __align__(16) __bf16 x_c[8 * XROW];
  __shared__ __align__(16) __bf16 h_bf[8 * HROW];
  __shared__ __align__(16) float  z_lds[8 * ZROW];

  const bool is_node = (int)blockIdx.x < 16;
  const int  bidx    = is_node ? blockIdx.x : ((int)blockIdx.x - 16);
  const float* __restrict__ Wih  = is_node ? Wih_n : Wih_e;
  const float* __restrict__ Whh  = is_node ? Whh_n : Whh_e;
  const float* __restrict__ bias = is_node ? b_n   : b_e;
  float* __restrict__ xh = (is_node ? xn : en) + (size_t)bidx * 8 * (T_ * HN_);

  const int tid = threadIdx.x;
  const int w   = tid >> 6;       // wave 0..7
  const int l   = tid & 63;
  const int lm  = l & 15;         // A-row / B-col index
  const int lh  = l >> 4;         // k-subgroup 0..3
  const int wcol0 = w * 64;

  // ---- weight fragments in registers (B operand: B[k][n], n=lm, k=kt*32+lh*8+j)
  bf16x8 wih_f[4][4], whh_f[4][4];
  float  bcol[4];
  #pragma unroll
  for (int nt = 0; nt < 4; ++nt) {
    const int n = wcol0 + nt*16 + lm;
    bcol[nt] = bias[n];
    #pragma unroll
    for (int kt = 0; kt < 4; ++kt) {
      #pragma unroll
      for (int j = 0; j < 8; ++j) {
        const int k = kt*32 + lh*8 + j;
        wih_f[nt][kt][j] = (__bf16)Wih[k*512 + n];
        whh_f[nt][kt][j] = (__bf16)Whh[k*512 + n];
      }
    }
  }

  for (int i = tid; i < 8 * HROW; i += 512) h_bf[i] = (__bf16)0.f;

  // gate-phase mapping: thread -> (seq, d0..d0+1)
  const int seqB = tid >> 6;
  const int d0   = (tid & 63) * 2;
  float c0 = 0.f, c1 = 0.f;

  const bool act  = lm < 8;       // A rows 8..15 are zero
  const int  srow = lm & 7;
  bf16x8 zfr;
  #pragma unroll
  for (int i = 0; i < 8; ++i) zfr[i] = (__bf16)0.f;

  for (int t = 0; t < T_; ++t) {
    if ((t & 15) == 0) {
      // stage 8 seq x 16 t x 128 k (f32 -> bf16). Safe vs in-place h writes:
      // h_t for this range is only written after staging completes.
      #pragma unroll
      for (int i = 0; i < 8; ++i) {
        const int f4  = (tid + i*512) * 4;
        const int s   = f4 >> 11;         // /(16*128)
        const int rem = f4 & 2047;        // tl*128 + k
        const float4 v = *reinterpret_cast<const float4*>(
            &xh[(size_t)s*(T_*HN_) + (size_t)t*HN_ + rem]);
        __bf16* p = &x_c[s*XROW + rem];
        p[0] = (__bf16)v.x; p[1] = (__bf16)v.y;
        p[2] = (__bf16)v.z; p[3] = (__bf16)v.w;
      }
      __syncthreads();
    }
    const int tl = t & 15;

    // ---- phase A: z = bias + x@Wih + h@Whh (MFMA)
    bf16x8 ax[4], ah[4];
    #pragma unroll
    for (int kt = 0; kt < 4; ++kt) {
      ax[kt] = act ? *reinterpret_cast<const bf16x8*>(
                       &x_c[srow*XROW + tl*128 + kt*32 + lh*8]) : zfr;
      ah[kt] = act ? *reinterpret_cast<const bf16x8*>(
                       &h_bf[srow*HROW + kt*32 + lh*8]) : zfr;
    }
    #pragma unroll
    for (int nt = 0; nt < 4; ++nt) {
      f32x4 acc = { bcol[nt], bcol[nt], bcol[nt], bcol[nt] };
      #pragma unroll
      for (int kt = 0; kt < 4; ++kt) {
        acc = __builtin_amdgcn_mfma_f32_16x16x32_bf16(ax[kt], wih_f[nt][kt], acc, 0, 0, 0);
        acc = __builtin_amdgcn_mfma_f32_16x16x32_bf16(ah[kt], whh_f[nt][kt], acc, 0, 0, 0);
      }
      if (l < 32) {   // D rows 0..7 live in lanes 0..31 (row = (l>>4)*4 + r)
        #pragma unroll
        for (int r = 0; r < 4; ++r)
          z_lds[(lh*4 + r)*ZROW + wcol0 + nt*16 + lm] = acc[r];
      }
    }
    __syncthreads();

    // ---- phase B: gates, c/h update
    {
      const float2 vi = *reinterpret_cast<const float2*>(&z_lds[seqB*ZROW +   0 + d0]);
      const float2 vf = *reinterpret_cast<const float2*>(&z_lds[seqB*ZROW + 128 + d0]);
      const float2 vg = *reinterpret_cast<const float2*>(&z_lds[seqB*ZROW + 256 + d0]);
      const float2 vo = *reinterpret_cast<const float2*>(&z_lds[seqB*ZROW + 384 + d0]);
      c0 = sigf(vf.x) * c0 + sigf(vi.x) * tanh_fast(vg.x);
      const float h0 = sigf(vo.x) * tanh_fast(c0);
      c1 = sigf(vf.y) * c1 + sigf(vi.y) * tanh_fast(vg.y);
      const float h1 = sigf(vo.y) * tanh_fast(c1);
      bf16x2 hb; hb[0] = (__bf16)h0; hb[1] = (__bf16)h1;
      *reinterpret_cast<bf16x2*>(&h_bf[seqB*HROW + d0]) = hb;
      float2 ho; ho.x = h0; ho.y = h1;
      *reinterpret_cast<float2*>(
          &xh[(size_t)seqB*(T_*HN_) + (size_t)t*HN_ + d0]) = ho;
    }
    __syncthreads();
  }
}

// ---------------- K4: gather + classifier (384 -> 256 -> 8)
__global__ __launch_bounds__(256) void classifier_kernel(
    const float* __restrict__ hn, const float* __restrict__ he,
    const float* __restrict__ Wc1, const float* __restrict__ bc1,
    const float* __restrict__ Wc2, const float* __restrict__ bc2,
    float* __restrict__ out)
{
  constexpr int HL = 132, HIDL = 260;
  __shared__ __align__(16) float hn_l[4][HL];
  __shared__ __align__(16) float he_l[16][HL];
  __shared__ __align__(16) float hid[16][HIDL];
  const int bt = blockIdx.x;
  const int b  = bt >> 9, t = bt & 511;
  const int j  = threadIdx.x;

  for (int idx = j; idx < 512; idx += 256) {
    const int n = idx >> 7, d = idx & 127;
    hn_l[n][d] = hn[((size_t)(b*4+n)*T_ + t)*HN_ + d];
  }
  for (int idx = j; idx < 2048; idx += 256) {
    const int e = idx >> 7, d = idx & 127;
    he_l[e][d] = he[((size_t)(b*16+e)*T_ + t)*HN_ + d];
  }
  __syncthreads();

  float acc[16];
  #pragma unroll
  for (int e = 0; e < 16; ++e) acc[e] = bc1[j];

  #pragma unroll 2
  for (int k4 = 0; k4 < 32; ++k4) {
    float4 w;
    w.x = Wc1[(k4*4+0)*256 + j];
    w.y = Wc1[(k4*4+1)*256 + j];
    w.z = Wc1[(k4*4+2)*256 + j];
    w.w = Wc1[(k4*4+3)*256 + j];
    float4 hv[4];
    #pragma unroll
    for (int n = 0; n < 4; ++n) hv[n] = *reinterpret_cast<const float4*>(&hn_l[n][k4*4]);
    #pragma unroll
    for (int e = 0; e < 16; ++e) {
      const float4 a = hv[e >> 2];
      acc[e] = fmaf(a.x, w.x, acc[e]);
      acc[e] = fmaf(a.y, w.y, acc[e]);
      acc[e] = fmaf(a.z, w.z, acc[e]);
      acc[e] = fmaf(a.w, w.w, acc[e]);
    }
  }
  #pragma unroll 2
  for (int k4 = 0; k4 < 32; ++k4) {
    float4 w;
    w.x = Wc1[(128 + k4*4+0)*256 + j];
    w.y = Wc1[(128 + k4*4+1)*256 + j];
    w.z = Wc1[(128 + k4*4+2)*256 + j];
    w.w = Wc1[(128 + k4*4+3)*256 + j];
    float4 hv[4];
    #pragma unroll
    for (int n = 0; n < 4; ++n) hv[n] = *reinterpret_cast<const float4*>(&hn_l[n][k4*4]);
    #pragma unroll
    for (int e = 0; e < 16; ++e) {
      const float4 a = hv[e & 3];
      acc[e] = fmaf(a.x, w.x, acc[e]);
      acc[e] = fmaf(a.y, w.y, acc[e]);
      acc[e] = fmaf(a.z, w.z, acc[e]);
      acc[e] = fmaf(a.w, w.w, acc[e]);
    }
  }
  #pragma unroll 2
  for (int k4 = 0; k4 < 32; ++k4) {
    float4 w;
    w.x = Wc1[(256 + k4*4+0)*256 + j];
    w.y = Wc1[(256 + k4*4+1)*256 + j];
    w.z = Wc1[(256 + k4*4+2)*256 + j];
    w.w = Wc1[(256 + k4*4+3)*256 + j];
    #pragma unroll
    for (int e = 0; e < 16; ++e) {
      const float4 a = *reinterpret_cast<const float4*>(&he_l[e][k4*4]);
      acc[e] = fmaf(a.x, w.x, acc[e]);
      acc[e] = fmaf(a.y, w.y, acc[e]);
      acc[e] = fmaf(a.z, w.z, acc[e]);
      acc[e] = fmaf(a.w, w.w, acc[e]);
    }
  }
  #pragma unroll
  for (int e = 0; e < 16; ++e) hid[e][j] = fmaxf(acc[e], 0.f);
  __syncthreads();

  if (j < 128) {
    const int e = j >> 3, c = j & 7;
    float p0 = bc2[c], p1 = 0.f, p2 = 0.f, p3 = 0.f;
    #pragma unroll 8
    for (int k4 = 0; k4 < 64; ++k4) {
      const float4 hq = *reinterpret_cast<const float4*>(&hid[e][k4*4]);
      p0 = fmaf(hq.x, Wc2[(k4*4+0)*8 + c], p0);
      p1 = fmaf(hq.y, Wc2[(k4*4+1)*8 + c], p1);
      p2 = fmaf(hq.z, Wc2[(k4*4+2)*8 + c], p2);
      p3 = fmaf(hq.w, Wc2[(k4*4+3)*8 + c], p3);
    }
    out[((size_t)bt * 16 + e) * 8 + c] = (p0 + p1) + (p2 + p3);
  }
}

extern "C" void kernel_launch(void* const* d_in, const int* in_sizes, int n_in,
                              void* d_out, int out_size, void* d_ws, size_t ws_size,
                              hipStream_t stream) {
  (void)in_sizes; (void)n_in; (void)out_size; (void)ws_size;
  const float* x_seq = (const float*)d_in[0];
  const float* ea    = (const float*)d_in[1];
  const float* Wn1 = (const float*)d_in[2];
  const float* bn1 = (const float*)d_in[3];
  const float* Wn2 = (const float*)d_in[4];
  const float* bn2 = (const float*)d_in[5];
  const float* We1 = (const float*)d_in[6];
  const float* be1 = (const float*)d_in[7];
  const float* We2 = (const float*)d_in[8];
  const float* be2 = (const float*)d_in[9];
  const float* Wg1 = (const float*)d_in[10];
  const float* bg1 = (const float*)d_in[11];
  const float* Wg2 = (const float*)d_in[12];
  const float* bg2 = (const float*)d_in[13];
  const float* Wef1 = (const float*)d_in[14];
  const float* bef1 = (const float*)d_in[15];
  const float* Wef2 = (const float*)d_in[16];
  const float* bef2 = (const float*)d_in[17];
  const float* Wih_n = (const float*)d_in[18];
  const float* Whh_n = (const float*)d_in[19];
  const float* b_n   = (const float*)d_in[20];
  const float* Wih_e = (const float*)d_in[21];
  const float* Whh_e = (const float*)d_in[22];
  const float* b_e   = (const float*)d_in[23];
  const float* Wc1 = (const float*)d_in[24];
  const float* bc1 = (const float*)d_in[25];
  const float* Wc2 = (const float*)d_in[26];
  const float* bc2 = (const float*)d_in[27];

  // workspace: xn/hn [128][512][128] f32 (33.5MB), en/he [512][512][128] f32 (134MB)
  float* xn = (float*)d_ws;
  float* en = xn + (size_t)128 * T_ * HN_;
  float* out = (float*)d_out;

  node_mlp_kernel<<<32*512, 128, 0, stream>>>(x_seq, Wn1, bn1, Wn2, bn2,
                                              Wg1, bg1, Wg2, bg2, xn);
  edge_mlp_kernel<<<32*512, 128, 0, stream>>>(ea, We1, be1, We2, be2,
                                              Wef1, bef1, Wef2, bef2, en);
  // 16 node blocks (128 seqs) + 64 edge blocks (512 seqs), 8 seqs each
  lstm_mfma_kernel<<<80, 512, 0, stream>>>(Wih_n, Whh_n, b_n,
                                           Wih_e, Whh_e, b_e, xn, en);
  classifier_kernel<<<32*512, 256, 0, stream>>>(xn, en, Wc1, bc1, Wc2, bc2, out);
}

// Round 3
// 1463.552 us; speedup vs baseline: 2.9566x; 1.4964x over previous
//
#include <hip/hip_runtime.h>
#include <cstdint>

// Problem constants (B,T,N,E)=(32,512,4,16), NI=16, EI=8, HN=HE=128, MH=256, C=8
constexpr int T_  = 512;
constexpr int HN_ = 128;

#define DEVI __device__ __forceinline__

typedef __bf16 bf16x8 __attribute__((ext_vector_type(8)));
typedef __bf16 bf16x2 __attribute__((ext_vector_type(2)));
typedef float  f32x4  __attribute__((ext_vector_type(4)));

DEVI float sigf(float x) { return __builtin_amdgcn_rcpf(1.f + __expf(-x)); }
DEVI float tanh_fast(float x) {
  x = fminf(fmaxf(x, -15.f), 15.f);
  return 1.f - 2.f * __builtin_amdgcn_rcpf(1.f + __expf(2.f * x));
}

// acc[n] += sum_k src[n*ld+k] * W[k*128 + d], K=128
template<int NR>
DEVI void layer128_acc(const float* __restrict__ src, int ld,
                       float* acc, const float* __restrict__ W, int d) {
  #pragma unroll 2
  for (int k4 = 0; k4 < 32; ++k4) {
    float4 w;
    w.x = W[(k4*4+0)*128 + d];
    w.y = W[(k4*4+1)*128 + d];
    w.z = W[(k4*4+2)*128 + d];
    w.w = W[(k4*4+3)*128 + d];
    #pragma unroll
    for (int n = 0; n < NR; ++n) {
      const float4 a = *reinterpret_cast<const float4*>(&src[n*ld + k4*4]);
      acc[n] = fmaf(a.x, w.x, acc[n]);
      acc[n] = fmaf(a.y, w.y, acc[n]);
      acc[n] = fmaf(a.z, w.z, acc[n]);
      acc[n] = fmaf(a.w, w.w, acc[n]);
    }
  }
}

// ---------------- K1: node MLP + 2 graph-conv layers -> xn [(b*4+n)][t][128]
__global__ __launch_bounds__(128) void node_mlp_kernel(
    const float* __restrict__ x_seq,
    const float* __restrict__ Wn1, const float* __restrict__ bn1,
    const float* __restrict__ Wn2, const float* __restrict__ bn2,
    const float* __restrict__ Wg1, const float* __restrict__ bg1,
    const float* __restrict__ Wg2, const float* __restrict__ bg2,
    float* __restrict__ xn)
{
  __shared__ __align__(16) float xs[4][16];
  __shared__ __align__(16) float A[4][128];
  __shared__ __align__(16) float Bb[4][128];
  const int bt = blockIdx.x;            // b*512 + t
  const int b  = bt >> 9, t = bt & 511;
  const int d  = threadIdx.x;

  if (d < 64) xs[d >> 4][d & 15] = x_seq[(size_t)bt * 64 + d];
  __syncthreads();

  float acc[4];
  {
    const float bv = bn1[d];
    #pragma unroll
    for (int n = 0; n < 4; ++n) acc[n] = bv;
    #pragma unroll
    for (int k = 0; k < 16; ++k) {
      const float w = Wn1[k*128 + d];
      #pragma unroll
      for (int n = 0; n < 4; ++n) acc[n] = fmaf(xs[n][k], w, acc[n]);
    }
    #pragma unroll
    for (int n = 0; n < 4; ++n) A[n][d] = fmaxf(acc[n], 0.f);
  }
  __syncthreads();
  {
    const float bv = bn2[d];
    #pragma unroll
    for (int n = 0; n < 4; ++n) acc[n] = bv;
    layer128_acc<4>(&A[0][0], 128, acc, Wn2, d);
    #pragma unroll
    for (int n = 0; n < 4; ++n) Bb[n][d] = fmaxf(acc[n], 0.f);
  }
  __syncthreads();
  {
    #pragma unroll
    for (int n = 0; n < 4; ++n) acc[n] = 0.f;
    layer128_acc<4>(&Bb[0][0], 128, acc, Wg1, d);
    #pragma unroll
    for (int n = 0; n < 4; ++n) A[n][d] = acc[n];
  }
  __syncthreads();
  {
    const float y0 = A[0][d], y1 = A[1][d], y2 = A[2][d], y3 = A[3][d];
    const float s = y0 + y1 + y2 + y3;
    const float bv = bg1[d];
    Bb[0][d] = fmaxf((s + y0) * 0.2f + bv, 0.f);
    Bb[1][d] = fmaxf((s + y1) * 0.2f + bv, 0.f);
    Bb[2][d] = fmaxf((s + y2) * 0.2f + bv, 0.f);
    Bb[3][d] = fmaxf((s + y3) * 0.2f + bv, 0.f);
  }
  __syncthreads();
  {
    #pragma unroll
    for (int n = 0; n < 4; ++n) acc[n] = 0.f;
    layer128_acc<4>(&Bb[0][0], 128, acc, Wg2, d);
    #pragma unroll
    for (int n = 0; n < 4; ++n) A[n][d] = acc[n];
  }
  __syncthreads();
  {
    const float y0 = A[0][d], y1 = A[1][d], y2 = A[2][d], y3 = A[3][d];
    const float s = y0 + y1 + y2 + y3;
    const float bv = bg2[d];
    xn[((size_t)(b*4+0)*T_ + t)*HN_ + d] = fmaxf((s + y0) * 0.2f + bv, 0.f);
    xn[((size_t)(b*4+1)*T_ + t)*HN_ + d] = fmaxf((s + y1) * 0.2f + bv, 0.f);
    xn[((size_t)(b*4+2)*T_ + t)*HN_ + d] = fmaxf((s + y2) * 0.2f + bv, 0.f);
    xn[((size_t)(b*4+3)*T_ + t)*HN_ + d] = fmaxf((s + y3) * 0.2f + bv, 0.f);
  }
}

// ---------------- K2: edge MLP (4 layers) -> en [(b*16+e)][t][128]
__global__ __launch_bounds__(128) void edge_mlp_kernel(
    const float* __restrict__ ea,
    const float* __restrict__ We1, const float* __restrict__ be1,
    const float* __restrict__ We2, const float* __restrict__ be2,
    const float* __restrict__ Wef1, const float* __restrict__ bef1,
    const float* __restrict__ Wef2, const float* __restrict__ bef2,
    float* __restrict__ en)
{
  __shared__ __align__(16) float es[16][8];
  __shared__ __align__(16) float A[16][128];
  __shared__ __align__(16) float Bb[16][128];
  const int bt = blockIdx.x;
  const int b  = bt >> 9, t = bt & 511;
  const int d  = threadIdx.x;

  es[d >> 3][d & 7] = ea[(size_t)bt * 128 + d];
  __syncthreads();

  float acc[16];
  {
    const float bv = be1[d];
    #pragma unroll
    for (int e = 0; e < 16; ++e) acc[e] = bv;
    #pragma unroll
    for (int k = 0; k < 8; ++k) {
      const float w = We1[k*128 + d];
      #pragma unroll
      for (int e = 0; e < 16; ++e) acc[e] = fmaf(es[e][k], w, acc[e]);
    }
    #pragma unroll
    for (int e = 0; e < 16; ++e) A[e][d] = fmaxf(acc[e], 0.f);
  }
  __syncthreads();
  {
    const float bv = be2[d];
    #pragma unroll
    for (int e = 0; e < 16; ++e) acc[e] = bv;
    layer128_acc<16>(&A[0][0], 128, acc, We2, d);
    #pragma unroll
    for (int e = 0; e < 16; ++e) Bb[e][d] = fmaxf(acc[e], 0.f);
  }
  __syncthreads();
  {
    const float bv = bef1[d];
    #pragma unroll
    for (int e = 0; e < 16; ++e) acc[e] = bv;
    layer128_acc<16>(&Bb[0][0], 128, acc, Wef1, d);
    #pragma unroll
    for (int e = 0; e < 16; ++e) A[e][d] = fmaxf(acc[e], 0.f);
  }
  __syncthreads();
  {
    const float bv = bef2[d];
    #pragma unroll
    for (int e = 0; e < 16; ++e) acc[e] = bv;
    layer128_acc<16>(&A[0][0], 128, acc, Wef2, d);
    #pragma unroll
    for (int e = 0; e < 16; ++e)
      en[((size_t)(b*16+e)*T_ + t)*HN_ + d] = fmaxf(acc[e], 0.f);
  }
}

// ---------------- K3: fused MFMA LSTM (node blocks 0..15, edge blocks 16..79)
__global__ __launch_bounds__(512, 2) void lstm_mfma_kernel(
    const float* __restrict__ Wih_n, const float* __restrict__ Whh_n,
    const float* __restrict__ b_n,
    const float* __restrict__ Wih_e, const float* __restrict__ Whh_e,
    const float* __restrict__ b_e,
    float* __restrict__ xn, float* __restrict__ en)
{
  constexpr int XROW = 2064;  // bf16 elems per seq row of x chunk (16*128 + 16 pad)
  constexpr int HROW = 144;   // bf16 elems per h row (128 + 16 pad)
  constexpr int ZROW = 520;   // f32 elems per z row (512 + 8 pad)
  __shared__ __align__(16) __bf16 x_c[8 * XROW];
  __shared__ __align__(16) __bf16 h_bf[8 * HROW];
  __shared__ __align__(16) float  z_lds[8 * ZROW];

  const bool is_node = (int)blockIdx.x < 16;
  const int  bidx    = is_node ? blockIdx.x : ((int)blockIdx.x - 16);
  const float* __restrict__ Wih  = is_node ? Wih_n : Wih_e;
  const float* __restrict__ Whh  = is_node ? Whh_n : Whh_e;
  const float* __restrict__ bias = is_node ? b_n   : b_e;
  float* __restrict__ xh = (is_node ? xn : en) + (size_t)bidx * 8 * (T_ * HN_);

  const int tid = threadIdx.x;
  const int w   = tid >> 6;       // wave 0..7
  const int l   = tid & 63;
  const int lm  = l & 15;         // A-row / B-col index
  const int lh  = l >> 4;         // k-subgroup 0..3
  const int wcol0 = w * 64;

  // ---- weight fragments in registers (B operand: B[k][n], n=lm, k=kt*32+lh*8+j)
  bf16x8 wih_f[4][4], whh_f[4][4];
  float  bcol[4];
  #pragma unroll
  for (int nt = 0; nt < 4; ++nt) {
    const int n = wcol0 + nt*16 + lm;
    bcol[nt] = bias[n];
    #pragma unroll
    for (int kt = 0; kt < 4; ++kt) {
      #pragma unroll
      for (int j = 0; j < 8; ++j) {
        const int k = kt*32 + lh*8 + j;
        wih_f[nt][kt][j] = (__bf16)Wih[k*512 + n];
        whh_f[nt][kt][j] = (__bf16)Whh[k*512 + n];
      }
    }
  }

  for (int i = tid; i < 8 * HROW; i += 512) h_bf[i] = (__bf16)0.f;

  const int seqB = tid >> 6;
  const int d0   = (tid & 63) * 2;
  float c0 = 0.f, c1 = 0.f;

  const bool act  = lm < 8;       // A rows 8..15 are zero
  const int  srow = lm & 7;
  bf16x8 zfr;
  #pragma unroll
  for (int i = 0; i < 8; ++i) zfr[i] = (__bf16)0.f;

  for (int t = 0; t < T_; ++t) {
    if ((t & 15) == 0) {
      #pragma unroll
      for (int i = 0; i < 8; ++i) {
        const int f4  = (tid + i*512) * 4;
        const int s   = f4 >> 11;         // /(16*128)
        const int rem = f4 & 2047;        // tl*128 + k
        const float4 v = *reinterpret_cast<const float4*>(
            &xh[(size_t)s*(T_*HN_) + (size_t)t*HN_ + rem]);
        __bf16* p = &x_c[s*XROW + rem];
        p[0] = (__bf16)v.x; p[1] = (__bf16)v.y;
        p[2] = (__bf16)v.z; p[3] = (__bf16)v.w;
      }
      __syncthreads();
    }
    const int tl = t & 15;

    // ---- phase A: z = bias + x@Wih + h@Whh (MFMA)
    bf16x8 ax[4], ah[4];
    #pragma unroll
    for (int kt = 0; kt < 4; ++kt) {
      ax[kt] = act ? *reinterpret_cast<const bf16x8*>(
                       &x_c[srow*XROW + tl*128 + kt*32 + lh*8]) : zfr;
      ah[kt] = act ? *reinterpret_cast<const bf16x8*>(
                       &h_bf[srow*HROW + kt*32 + lh*8]) : zfr;
    }
    #pragma unroll
    for (int nt = 0; nt < 4; ++nt) {
      f32x4 acc = { bcol[nt], bcol[nt], bcol[nt], bcol[nt] };
      #pragma unroll
      for (int kt = 0; kt < 4; ++kt) {
        acc = __builtin_amdgcn_mfma_f32_16x16x32_bf16(ax[kt], wih_f[nt][kt], acc, 0, 0, 0);
        acc = __builtin_amdgcn_mfma_f32_16x16x32_bf16(ah[kt], whh_f[nt][kt], acc, 0, 0, 0);
      }
      if (l < 32) {   // D rows 0..7 live in lanes 0..31 (row = (l>>4)*4 + r)
        #pragma unroll
        for (int r = 0; r < 4; ++r)
          z_lds[(lh*4 + r)*ZROW + wcol0 + nt*16 + lm] = acc[r];
      }
    }
    __syncthreads();

    // ---- phase B: gates, c/h update
    {
      const float2 vi = *reinterpret_cast<const float2*>(&z_lds[seqB*ZROW +   0 + d0]);
      const float2 vf = *reinterpret_cast<const float2*>(&z_lds[seqB*ZROW + 128 + d0]);
      const float2 vg = *reinterpret_cast<const float2*>(&z_lds[seqB*ZROW + 256 + d0]);
      const float2 vo = *reinterpret_cast<const float2*>(&z_lds[seqB*ZROW + 384 + d0]);
      c0 = sigf(vf.x) * c0 + sigf(vi.x) * tanh_fast(vg.x);
      const float h0 = sigf(vo.x) * tanh_fast(c0);
      c1 = sigf(vf.y) * c1 + sigf(vi.y) * tanh_fast(vg.y);
      const float h1 = sigf(vo.y) * tanh_fast(c1);
      bf16x2 hb; hb[0] = (__bf16)h0; hb[1] = (__bf16)h1;
      *reinterpret_cast<bf16x2*>(&h_bf[seqB*HROW + d0]) = hb;
      float2 ho; ho.x = h0; ho.y = h1;
      *reinterpret_cast<float2*>(
          &xh[(size_t)seqB*(T_*HN_) + (size_t)t*HN_ + d0]) = ho;
    }
    __syncthreads();
  }
}

// ---------------- K4: MFMA gather + classifier (384 -> 256 -> 8)
// Persistent: 256 blocks x 512 thr (8 waves), each block loops 8 (b,t0) groups
// of 8 timesteps. Wave w owns hidden cols [32w,32w+32); Wc1/Wc2 B-fragments in
// VGPRs loaded once. Phase 1: hidden=relu(feats@Wc1+bc1) -> LDS bf16.
// Phase 2: wave w takes t=w: logits = hidden@Wc2 + bc2 (B cols 8..15 zero).
__global__ __launch_bounds__(512, 1) void classifier_mfma_kernel(
    const float* __restrict__ hn, const float* __restrict__ he,
    const float* __restrict__ Wc1, const float* __restrict__ bc1,
    const float* __restrict__ Wc2, const float* __restrict__ bc2,
    float* __restrict__ out)
{
  constexpr int HP = 136;    // bf16 pitch for hn_l/he_l rows (272B -> 4-bank shift)
  constexpr int DP = 264;    // bf16 pitch for hidden rows (528B -> 4-bank shift)
  __shared__ __align__(16) __bf16 hn_l[32 * HP];    //  8704 B : rows (t,n)
  __shared__ __align__(16) __bf16 he_l[128 * HP];   // 34816 B : rows (t,e)
  __shared__ __align__(16) __bf16 hid_l[128 * DP];  // 67584 B : rows (t,e)

  const int tid = threadIdx.x;
  const int w   = tid >> 6;
  const int l   = tid & 63;
  const int lm  = l & 15;
  const int lh  = l >> 4;

  // ---- B-fragments (once): Wc1 cols [32w,32w+32), 12 k-tiles of 32
  bf16x8 wb[2][12];
  float  bcol[2];
  #pragma unroll
  for (int jt = 0; jt < 2; ++jt) {
    const int j = w*32 + jt*16 + lm;
    bcol[jt] = bc1[j];
    #pragma unroll
    for (int kt = 0; kt < 12; ++kt)
      #pragma unroll
      for (int i = 0; i < 8; ++i)
        wb[jt][kt][i] = (__bf16)Wc1[(kt*32 + lh*8 + i)*256 + j];
  }
  bf16x8 wc2f[8];
  const float bc2v = (lm < 8) ? bc2[lm] : 0.f;
  #pragma unroll
  for (int kt = 0; kt < 8; ++kt)
    #pragma unroll
    for (int i = 0; i < 8; ++i)
      wc2f[kt][i] = (lm < 8) ? (__bf16)Wc2[(kt*32 + lh*8 + i)*8 + lm] : (__bf16)0.f;

  for (int g = blockIdx.x; g < 2048; g += 256) {
    const int b  = g >> 6;
    const int t0 = (g & 63) * 8;

    // ---- stage: he 16e x 8t x 128, hn 4n x 8t x 128 (f32 -> bf16)
    for (int i = tid; i < 4096; i += 512) {
      const int f4 = i * 4;
      const int e  = f4 >> 10;
      const int rem = f4 & 1023;
      const int tt = rem >> 7;
      const int k  = rem & 127;
      const float4 v = *reinterpret_cast<const float4*>(
          &he[((size_t)(b*16+e)*T_ + t0 + tt)*HN_ + k]);
      __bf16* p = &he_l[(tt*16 + e)*HP + k];
      p[0]=(__bf16)v.x; p[1]=(__bf16)v.y; p[2]=(__bf16)v.z; p[3]=(__bf16)v.w;
    }
    for (int i = tid; i < 1024; i += 512) {
      const int f4 = i * 4;
      const int n  = f4 >> 10;
      const int rem = f4 & 1023;
      const int tt = rem >> 7;
      const int k  = rem & 127;
      const float4 v = *reinterpret_cast<const float4*>(
          &hn[((size_t)(b*4+n)*T_ + t0 + tt)*HN_ + k]);
      __bf16* p = &hn_l[(tt*4 + n)*HP + k];
      p[0]=(__bf16)v.x; p[1]=(__bf16)v.y; p[2]=(__bf16)v.z; p[3]=(__bf16)v.w;
    }
    __syncthreads();

    // ---- phase 1: hidden = relu(feats @ Wc1 + bc1), A-row = e (lm)
    for (int tt = 0; tt < 8; ++tt) {
      bf16x8 af[12];
      #pragma unroll
      for (int kt = 0; kt < 4; ++kt)
        af[kt] = *reinterpret_cast<const bf16x8*>(
            &hn_l[(tt*4 + (lm>>2))*HP + kt*32 + lh*8]);      // src node
      #pragma unroll
      for (int kt = 0; kt < 4; ++kt)
        af[4+kt] = *reinterpret_cast<const bf16x8*>(
            &hn_l[(tt*4 + (lm&3))*HP + kt*32 + lh*8]);       // dst node
      #pragma unroll
      for (int kt = 0; kt < 4; ++kt)
        af[8+kt] = *reinterpret_cast<const bf16x8*>(
            &he_l[(tt*16 + lm)*HP + kt*32 + lh*8]);          // edge
      #pragma unroll
      for (int jt = 0; jt < 2; ++jt) {
        f32x4 acc = { bcol[jt], bcol[jt], bcol[jt], bcol[jt] };
        #pragma unroll
        for (int kt = 0; kt < 12; ++kt)
          acc = __builtin_amdgcn_mfma_f32_16x16x32_bf16(af[kt], wb[jt][kt], acc, 0, 0, 0);
        #pragma unroll
        for (int r = 0; r < 4; ++r)
          hid_l[(tt*16 + lh*4 + r)*DP + (w*2 + jt)*16 + lm] = (__bf16)fmaxf(acc[r], 0.f);
      }
    }
    __syncthreads();

    // ---- phase 2: wave w -> t=w: logits = hidden @ Wc2 + bc2
    {
      const int tt = w;
      f32x4 acc = { bc2v, bc2v, bc2v, bc2v };
      #pragma unroll
      for (int kt = 0; kt < 8; ++kt) {
        const bf16x8 a = *reinterpret_cast<const bf16x8*>(
            &hid_l[(tt*16 + lm)*DP + kt*32 + lh*8]);
        acc = __builtin_amdgcn_mfma_f32_16x16x32_bf16(a, wc2f[kt], acc, 0, 0, 0);
      }
      if (lm < 8) {
        const size_t bt = (size_t)b*T_ + t0 + tt;
        #pragma unroll
        for (int r = 0; r < 4; ++r)
          out[(bt*16 + lh*4 + r)*8 + lm] = acc[r];
      }
    }
    __syncthreads();   // protect hn_l/he_l/hid_l before next group's staging
  }
}

extern "C" void kernel_launch(void* const* d_in, const int* in_sizes, int n_in,
                              void* d_out, int out_size, void* d_ws, size_t ws_size,
                              hipStream_t stream) {
  (void)in_sizes; (void)n_in; (void)out_size; (void)ws_size;
  const float* x_seq = (const float*)d_in[0];
  const float* ea    = (const float*)d_in[1];
  const float* Wn1 = (const float*)d_in[2];
  const float* bn1 = (const float*)d_in[3];
  const float* Wn2 = (const float*)d_in[4];
  const float* bn2 = (const float*)d_in[5];
  const float* We1 = (const float*)d_in[6];
  const float* be1 = (const float*)d_in[7];
  const float* We2 = (const float*)d_in[8];
  const float* be2 = (const float*)d_in[9];
  const float* Wg1 = (const float*)d_in[10];
  const float* bg1 = (const float*)d_in[11];
  const float* Wg2 = (const float*)d_in[12];
  const float* bg2 = (const float*)d_in[13];
  const float* Wef1 = (const float*)d_in[14];
  const float* bef1 = (const float*)d_in[15];
  const float* Wef2 = (const float*)d_in[16];
  const float* bef2 = (const float*)d_in[17];
  const float* Wih_n = (const float*)d_in[18];
  const float* Whh_n = (const float*)d_in[19];
  const float* b_n   = (const float*)d_in[20];
  const float* Wih_e = (const float*)d_in[21];
  const float* Whh_e = (const float*)d_in[22];
  const float* b_e   = (const float*)d_in[23];
  const float* Wc1 = (const float*)d_in[24];
  const float* bc1 = (const float*)d_in[25];
  const float* Wc2 = (const float*)d_in[26];
  const float* bc2 = (const float*)d_in[27];

  // workspace: xn/hn [128][512][128] f32 (33.5MB), en/he [512][512][128] f32 (134MB)
  float* xn = (float*)d_ws;
  float* en = xn + (size_t)128 * T_ * HN_;
  float* out = (float*)d_out;

  node_mlp_kernel<<<32*512, 128, 0, stream>>>(x_seq, Wn1, bn1, Wn2, bn2,
                                              Wg1, bg1, Wg2, bg2, xn);
  edge_mlp_kernel<<<32*512, 128, 0, stream>>>(ea, We1, be1, We2, be2,
                                              Wef1, bef1, Wef2, bef2, en);
  lstm_mfma_kernel<<<80, 512, 0, stream>>>(Wih_n, Whh_n, b_n,
                                           Wih_e, Whh_e, b_e, xn, en);
  classifier_mfma_kernel<<<256, 512, 0, stream>>>(xn, en, Wc1, bc1, Wc2, bc2, out);
}

// Round 4
// 1334.561 us; speedup vs baseline: 3.2423x; 1.0967x over previous
//
#include <hip/hip_runtime.h>
#include <cstdint>

// Problem constants (B,T,N,E)=(32,512,4,16), NI=16, EI=8, HN=HE=128, MH=256, C=8
constexpr int T_  = 512;
constexpr int HN_ = 128;

#define DEVI __device__ __forceinline__

typedef __bf16 bf16x8 __attribute__((ext_vector_type(8)));
typedef __bf16 bf16x4 __attribute__((ext_vector_type(4)));
typedef __bf16 bf16x2 __attribute__((ext_vector_type(2)));
typedef float  f32x4  __attribute__((ext_vector_type(4)));

DEVI float sigf(float x) { return __builtin_amdgcn_rcpf(1.f + __expf(-x)); }
DEVI float tanh_fast(float x) {
  x = fminf(fmaxf(x, -15.f), 15.f);
  return 1.f - 2.f * __builtin_amdgcn_rcpf(1.f + __expf(2.f * x));
}

// acc[n] += sum_k src[n*ld+k] * W[k*128 + d], K=128
template<int NR>
DEVI void layer128_acc(const float* __restrict__ src, int ld,
                       float* acc, const float* __restrict__ W, int d) {
  #pragma unroll 2
  for (int k4 = 0; k4 < 32; ++k4) {
    float4 w;
    w.x = W[(k4*4+0)*128 + d];
    w.y = W[(k4*4+1)*128 + d];
    w.z = W[(k4*4+2)*128 + d];
    w.w = W[(k4*4+3)*128 + d];
    #pragma unroll
    for (int n = 0; n < NR; ++n) {
      const float4 a = *reinterpret_cast<const float4*>(&src[n*ld + k4*4]);
      acc[n] = fmaf(a.x, w.x, acc[n]);
      acc[n] = fmaf(a.y, w.y, acc[n]);
      acc[n] = fmaf(a.z, w.z, acc[n]);
      acc[n] = fmaf(a.w, w.w, acc[n]);
    }
  }
}

// ---------------- K1: node MLP + 2 graph-conv layers -> xn [(b*4+n)][t][128]
__global__ __launch_bounds__(128) void node_mlp_kernel(
    const float* __restrict__ x_seq,
    const float* __restrict__ Wn1, const float* __restrict__ bn1,
    const float* __restrict__ Wn2, const float* __restrict__ bn2,
    const float* __restrict__ Wg1, const float* __restrict__ bg1,
    const float* __restrict__ Wg2, const float* __restrict__ bg2,
    float* __restrict__ xn)
{
  __shared__ __align__(16) float xs[4][16];
  __shared__ __align__(16) float A[4][128];
  __shared__ __align__(16) float Bb[4][128];
  const int bt = blockIdx.x;            // b*512 + t
  const int b  = bt >> 9, t = bt & 511;
  const int d  = threadIdx.x;

  if (d < 64) xs[d >> 4][d & 15] = x_seq[(size_t)bt * 64 + d];
  __syncthreads();

  float acc[4];
  {
    const float bv = bn1[d];
    #pragma unroll
    for (int n = 0; n < 4; ++n) acc[n] = bv;
    #pragma unroll
    for (int k = 0; k < 16; ++k) {
      const float w = Wn1[k*128 + d];
      #pragma unroll
      for (int n = 0; n < 4; ++n) acc[n] = fmaf(xs[n][k], w, acc[n]);
    }
    #pragma unroll
    for (int n = 0; n < 4; ++n) A[n][d] = fmaxf(acc[n], 0.f);
  }
  __syncthreads();
  {
    const float bv = bn2[d];
    #pragma unroll
    for (int n = 0; n < 4; ++n) acc[n] = bv;
    layer128_acc<4>(&A[0][0], 128, acc, Wn2, d);
    #pragma unroll
    for (int n = 0; n < 4; ++n) Bb[n][d] = fmaxf(acc[n], 0.f);
  }
  __syncthreads();
  {
    #pragma unroll
    for (int n = 0; n < 4; ++n) acc[n] = 0.f;
    layer128_acc<4>(&Bb[0][0], 128, acc, Wg1, d);
    #pragma unroll
    for (int n = 0; n < 4; ++n) A[n][d] = acc[n];
  }
  __syncthreads();
  {
    const float y0 = A[0][d], y1 = A[1][d], y2 = A[2][d], y3 = A[3][d];
    const float s = y0 + y1 + y2 + y3;
    const float bv = bg1[d];
    Bb[0][d] = fmaxf((s + y0) * 0.2f + bv, 0.f);
    Bb[1][d] = fmaxf((s + y1) * 0.2f + bv, 0.f);
    Bb[2][d] = fmaxf((s + y2) * 0.2f + bv, 0.f);
    Bb[3][d] = fmaxf((s + y3) * 0.2f + bv, 0.f);
  }
  __syncthreads();
  {
    #pragma unroll
    for (int n = 0; n < 4; ++n) acc[n] = 0.f;
    layer128_acc<4>(&Bb[0][0], 128, acc, Wg2, d);
    #pragma unroll
    for (int n = 0; n < 4; ++n) A[n][d] = acc[n];
  }
  __syncthreads();
  {
    const float y0 = A[0][d], y1 = A[1][d], y2 = A[2][d], y3 = A[3][d];
    const float s = y0 + y1 + y2 + y3;
    const float bv = bg2[d];
    xn[((size_t)(b*4+0)*T_ + t)*HN_ + d] = fmaxf((s + y0) * 0.2f + bv, 0.f);
    xn[((size_t)(b*4+1)*T_ + t)*HN_ + d] = fmaxf((s + y1) * 0.2f + bv, 0.f);
    xn[((size_t)(b*4+2)*T_ + t)*HN_ + d] = fmaxf((s + y2) * 0.2f + bv, 0.f);
    xn[((size_t)(b*4+3)*T_ + t)*HN_ + d] = fmaxf((s + y3) * 0.2f + bv, 0.f);
  }
}

// ---------------- K2: edge MLP (4 layers) -> en [(b*16+e)][t][128]
__global__ __launch_bounds__(128) void edge_mlp_kernel(
    const float* __restrict__ ea,
    const float* __restrict__ We1, const float* __restrict__ be1,
    const float* __restrict__ We2, const float* __restrict__ be2,
    const float* __restrict__ Wef1, const float* __restrict__ bef1,
    const float* __restrict__ Wef2, const float* __restrict__ bef2,
    float* __restrict__ en)
{
  __shared__ __align__(16) float es[16][8];
  __shared__ __align__(16) float A[16][128];
  __shared__ __align__(16) float Bb[16][128];
  const int bt = blockIdx.x;
  const int b  = bt >> 9, t = bt & 511;
  const int d  = threadIdx.x;

  es[d >> 3][d & 7] = ea[(size_t)bt * 128 + d];
  __syncthreads();

  float acc[16];
  {
    const float bv = be1[d];
    #pragma unroll
    for (int e = 0; e < 16; ++e) acc[e] = bv;
    #pragma unroll
    for (int k = 0; k < 8; ++k) {
      const float w = We1[k*128 + d];
      #pragma unroll
      for (int e = 0; e < 16; ++e) acc[e] = fmaf(es[e][k], w, acc[e]);
    }
    #pragma unroll
    for (int e = 0; e < 16; ++e) A[e][d] = fmaxf(acc[e], 0.f);
  }
  __syncthreads();
  {
    const float bv = be2[d];
    #pragma unroll
    for (int e = 0; e < 16; ++e) acc[e] = bv;
    layer128_acc<16>(&A[0][0], 128, acc, We2, d);
    #pragma unroll
    for (int e = 0; e < 16; ++e) Bb[e][d] = fmaxf(acc[e], 0.f);
  }
  __syncthreads();
  {
    const float bv = bef1[d];
    #pragma unroll
    for (int e = 0; e < 16; ++e) acc[e] = bv;
    layer128_acc<16>(&Bb[0][0], 128, acc, Wef1, d);
    #pragma unroll
    for (int e = 0; e < 16; ++e) A[e][d] = fmaxf(acc[e], 0.f);
  }
  __syncthreads();
  {
    const float bv = bef2[d];
    #pragma unroll
    for (int e = 0; e < 16; ++e) acc[e] = bv;
    layer128_acc<16>(&A[0][0], 128, acc, Wef2, d);
    #pragma unroll
    for (int e = 0; e < 16; ++e)
      en[((size_t)(b*16+e)*T_ + t)*HN_ + d] = fmaxf(acc[e], 0.f);
  }
}

// ---------------- K3: fused MFMA LSTM, swapped operands (z^T = W^T @ x/h^T)
// Node blocks 0..15 (128 seqs), edge blocks 16..79 (512 seqs), 8 seqs/block.
// Wave w owns dims [16w,16w+16) x all 4 gate types (i,f,g,o at nt*128).
// A = W^T fragments in VGPRs (row=gate), B = x/h rows from LDS (col=seq).
// D: col=seq(lm), row=gate-within-tile(lh*4+r) -> gates fully in-register,
// ONE barrier per step, no z_lds. Lanes lm>=8 take r=2,3 via shfl_up
// (halves transcendental instruction count). Seq cols 8..15 masked via
// zero-row pointers (no per-step selects).
__global__ __launch_bounds__(512, 2) void lstm_mfma_kernel(
    const float* __restrict__ Wih_n, const float* __restrict__ Whh_n,
    const float* __restrict__ b_n,
    const float* __restrict__ Wih_e, const float* __restrict__ Whh_e,
    const float* __restrict__ b_e,
    float* __restrict__ xn, float* __restrict__ en)
{
  constexpr int XROW = 2064;  // bf16 per seq row of x chunk (16*128 + 16 pad)
  constexpr int HROW = 144;   // bf16 per h row (128 + 16 pad)
  __shared__ __align__(16) __bf16 x_c[8 * XROW];
  __shared__ __align__(16) __bf16 x_zero[XROW];
  __shared__ __align__(16) __bf16 h_bf[8 * HROW];
  __shared__ __align__(16) __bf16 h_zero[HROW];

  const bool is_node = (int)blockIdx.x < 16;
  const int  bidx    = is_node ? blockIdx.x : ((int)blockIdx.x - 16);
  const float* __restrict__ Wih  = is_node ? Wih_n : Wih_e;
  const float* __restrict__ Whh  = is_node ? Whh_n : Whh_e;
  const float* __restrict__ bias = is_node ? b_n   : b_e;
  float* __restrict__ xh = (is_node ? xn : en) + (size_t)bidx * 8 * (T_ * HN_);

  const int tid = threadIdx.x;
  const int w   = tid >> 6;       // wave 0..7 -> dims [16w,16w+16)
  const int l   = tid & 63;
  const int lm  = l & 15;         // B col (seq) / A row (gate)
  const int lh  = l >> 4;         // k-subgroup 0..3

  // ---- A-operand fragments: A[m][k] = W[k][gate], m=lm, k=kt*32+lh*8+j
  bf16x8 wih_f[4][4], whh_f[4][4];
  f32x4  bias_v[4];
  #pragma unroll
  for (int nt = 0; nt < 4; ++nt) {
    const int g0 = nt*128 + w*16;
    bias_v[nt] = *reinterpret_cast<const f32x4*>(&bias[g0 + lh*4]);
    #pragma unroll
    for (int kt = 0; kt < 4; ++kt) {
      #pragma unroll
      for (int j = 0; j < 8; ++j) {
        const int k = kt*32 + lh*8 + j;
        wih_f[nt][kt][j] = (__bf16)Wih[k*512 + g0 + lm];
        whh_f[nt][kt][j] = (__bf16)Whh[k*512 + g0 + lm];
      }
    }
  }

  // zero inits (barrier after first staging covers these)
  for (int i = tid; i < XROW; i += 512) x_zero[i] = (__bf16)0.f;
  for (int i = tid; i < 8 * HROW; i += 512) h_bf[i] = (__bf16)0.f;
  if (tid < HROW) h_zero[tid] = (__bf16)0.f;

  // B-row pointers with zero-masking for seq cols 8..15
  const __bf16* __restrict__ xrow = (lm < 8) ? &x_c[lm * XROW] : x_zero;
  const __bf16* __restrict__ hrow = (lm < 8) ? &h_bf[lm * HROW] : h_zero;

  const bool hi_half = lm >= 8;
  const int  s  = lm & 7;                         // seq for gate phase
  const int  dl = w*16 + lh*4 + (hi_half ? 2 : 0); // dim pair base
  float c0 = 0.f, c1 = 0.f;

  for (int t = 0; t < T_; ++t) {
    if ((t & 15) == 0) {
      // stage 8 seq x 16 t x 128 k (f32 -> bf16, packed 8B stores)
      #pragma unroll
      for (int i = 0; i < 8; ++i) {
        const int f4  = (tid + i*512) * 4;
        const int sq  = f4 >> 11;         // /(16*128)
        const int rem = f4 & 2047;        // tl*128 + k
        const float4 v = *reinterpret_cast<const float4*>(
            &xh[(size_t)sq*(T_*HN_) + (size_t)t*HN_ + rem]);
        bf16x4 pk;
        pk[0] = (__bf16)v.x; pk[1] = (__bf16)v.y;
        pk[2] = (__bf16)v.z; pk[3] = (__bf16)v.w;
        *reinterpret_cast<bf16x4*>(&x_c[sq*XROW + rem]) = pk;
      }
      __syncthreads();
    }
    const int tl = t & 15;

    // ---- B-operand reads (seq cols; rows 8..15 read zero rows)
    bf16x8 bx[4], bh[4];
    #pragma unroll
    for (int kt = 0; kt < 4; ++kt) {
      bx[kt] = *reinterpret_cast<const bf16x8*>(&xrow[tl*128 + kt*32 + lh*8]);
      bh[kt] = *reinterpret_cast<const bf16x8*>(&hrow[kt*32 + lh*8]);
    }

    // ---- z^T = bias + Wih^T@x + Whh^T@h (4 gate-type tiles)
    f32x4 accs[4];
    #pragma unroll
    for (int nt = 0; nt < 4; ++nt) {
      f32x4 acc = bias_v[nt];
      #pragma unroll
      for (int kt = 0; kt < 4; ++kt) {
        acc = __builtin_amdgcn_mfma_f32_16x16x32_bf16(wih_f[nt][kt], bx[kt], acc, 0, 0, 0);
        acc = __builtin_amdgcn_mfma_f32_16x16x32_bf16(whh_f[nt][kt], bh[kt], acc, 0, 0, 0);
      }
      accs[nt] = acc;
    }

    // ---- in-register gates; lanes lm>=8 handle rows r=2,3 (via shfl_up 8)
    float z0[4], z1[4];
    #pragma unroll
    for (int nt = 0; nt < 4; ++nt) {
      const float a2 = __shfl_up(accs[nt][2], 8u, 16);
      const float a3 = __shfl_up(accs[nt][3], 8u, 16);
      z0[nt] = hi_half ? a2 : accs[nt][0];
      z1[nt] = hi_half ? a3 : accs[nt][1];
    }
    c0 = sigf(z0[1]) * c0 + sigf(z0[0]) * tanh_fast(z0[2]);
    const float h0 = sigf(z0[3]) * tanh_fast(c0);
    c1 = sigf(z1[1]) * c1 + sigf(z1[0]) * tanh_fast(z1[2]);
    const float h1 = sigf(z1[3]) * tanh_fast(c1);

    bf16x2 hb; hb[0] = (__bf16)h0; hb[1] = (__bf16)h1;
    *reinterpret_cast<bf16x2*>(&h_bf[s*HROW + dl]) = hb;
    float2 ho; ho.x = h0; ho.y = h1;
    *reinterpret_cast<float2*>(
        &xh[(size_t)s*(T_*HN_) + (size_t)t*HN_ + dl]) = ho;
    __syncthreads();
  }
}

// ---------------- K4: MFMA gather + classifier (384 -> 256 -> 8)
__global__ __launch_bounds__(512, 1) void classifier_mfma_kernel(
    const float* __restrict__ hn, const float* __restrict__ he,
    const float* __restrict__ Wc1, const float* __restrict__ bc1,
    const float* __restrict__ Wc2, const float* __restrict__ bc2,
    float* __restrict__ out)
{
  constexpr int HP = 136;    // bf16 pitch for hn_l/he_l rows
  constexpr int DP = 264;    // bf16 pitch for hidden rows
  __shared__ __align__(16) __bf16 hn_l[32 * HP];
  __shared__ __align__(16) __bf16 he_l[128 * HP];
  __shared__ __align__(16) __bf16 hid_l[128 * DP];

  const int tid = threadIdx.x;
  const int w   = tid >> 6;
  const int l   = tid & 63;
  const int lm  = l & 15;
  const int lh  = l >> 4;

  bf16x8 wb[2][12];
  float  bcol[2];
  #pragma unroll
  for (int jt = 0; jt < 2; ++jt) {
    const int j = w*32 + jt*16 + lm;
    bcol[jt] = bc1[j];
    #pragma unroll
    for (int kt = 0; kt < 12; ++kt)
      #pragma unroll
      for (int i = 0; i < 8; ++i)
        wb[jt][kt][i] = (__bf16)Wc1[(kt*32 + lh*8 + i)*256 + j];
  }
  bf16x8 wc2f[8];
  const float bc2v = (lm < 8) ? bc2[lm] : 0.f;
  #pragma unroll
  for (int kt = 0; kt < 8; ++kt)
    #pragma unroll
    for (int i = 0; i < 8; ++i)
      wc2f[kt][i] = (lm < 8) ? (__bf16)Wc2[(kt*32 + lh*8 + i)*8 + lm] : (__bf16)0.f;

  for (int g = blockIdx.x; g < 2048; g += 256) {
    const int b  = g >> 6;
    const int t0 = (g & 63) * 8;

    for (int i = tid; i < 4096; i += 512) {
      const int f4 = i * 4;
      const int e  = f4 >> 10;
      const int rem = f4 & 1023;
      const int tt = rem >> 7;
      const int k  = rem & 127;
      const float4 v = *reinterpret_cast<const float4*>(
          &he[((size_t)(b*16+e)*T_ + t0 + tt)*HN_ + k]);
      __bf16* p = &he_l[(tt*16 + e)*HP + k];
      p[0]=(__bf16)v.x; p[1]=(__bf16)v.y; p[2]=(__bf16)v.z; p[3]=(__bf16)v.w;
    }
    for (int i = tid; i < 1024; i += 512) {
      const int f4 = i * 4;
      const int n  = f4 >> 10;
      const int rem = f4 & 1023;
      const int tt = rem >> 7;
      const int k  = rem & 127;
      const float4 v = *reinterpret_cast<const float4*>(
          &hn[((size_t)(b*4+n)*T_ + t0 + tt)*HN_ + k]);
      __bf16* p = &hn_l[(tt*4 + n)*HP + k];
      p[0]=(__bf16)v.x; p[1]=(__bf16)v.y; p[2]=(__bf16)v.z; p[3]=(__bf16)v.w;
    }
    __syncthreads();

    for (int tt = 0; tt < 8; ++tt) {
      bf16x8 af[12];
      #pragma unroll
      for (int kt = 0; kt < 4; ++kt)
        af[kt] = *reinterpret_cast<const bf16x8*>(
            &hn_l[(tt*4 + (lm>>2))*HP + kt*32 + lh*8]);
      #pragma unroll
      for (int kt = 0; kt < 4; ++kt)
        af[4+kt] = *reinterpret_cast<const bf16x8*>(
            &hn_l[(tt*4 + (lm&3))*HP + kt*32 + lh*8]);
      #pragma unroll
      for (int kt = 0; kt < 4; ++kt)
        af[8+kt] = *reinterpret_cast<const bf16x8*>(
            &he_l[(tt*16 + lm)*HP + kt*32 + lh*8]);
      #pragma unroll
      for (int jt = 0; jt < 2; ++jt) {
        f32x4 acc = { bcol[jt], bcol[jt], bcol[jt], bcol[jt] };
        #pragma unroll
        for (int kt = 0; kt < 12; ++kt)
          acc = __builtin_amdgcn_mfma_f32_16x16x32_bf16(af[kt], wb[jt][kt], acc, 0, 0, 0);
        #pragma unroll
        for (int r = 0; r < 4; ++r)
          hid_l[(tt*16 + lh*4 + r)*DP + (w*2 + jt)*16 + lm] = (__bf16)fmaxf(acc[r], 0.f);
      }
    }
    __syncthreads();

    {
      const int tt = w;
      f32x4 acc = { bc2v, bc2v, bc2v, bc2v };
      #pragma unroll
      for (int kt = 0; kt < 8; ++kt) {
        const bf16x8 a = *reinterpret_cast<const bf16x8*>(
            &hid_l[(tt*16 + lm)*DP + kt*32 + lh*8]);
        acc = __builtin_amdgcn_mfma_f32_16x16x32_bf16(a, wc2f[kt], acc, 0, 0, 0);
      }
      if (lm < 8) {
        const size_t bt = (size_t)b*T_ + t0 + tt;
        #pragma unroll
        for (int r = 0; r < 4; ++r)
          out[(bt*16 + lh*4 + r)*8 + lm] = acc[r];
      }
    }
    __syncthreads();
  }
}

extern "C" void kernel_launch(void* const* d_in, const int* in_sizes, int n_in,
                              void* d_out, int out_size, void* d_ws, size_t ws_size,
                              hipStream_t stream) {
  (void)in_sizes; (void)n_in; (void)out_size; (void)ws_size;
  const float* x_seq = (const float*)d_in[0];
  const float* ea    = (const float*)d_in[1];
  const float* Wn1 = (const float*)d_in[2];
  const float* bn1 = (const float*)d_in[3];
  const float* Wn2 = (const float*)d_in[4];
  const float* bn2 = (const float*)d_in[5];
  const float* We1 = (const float*)d_in[6];
  const float* be1 = (const float*)d_in[7];
  const float* We2 = (const float*)d_in[8];
  const float* be2 = (const float*)d_in[9];
  const float* Wg1 = (const float*)d_in[10];
  const float* bg1 = (const float*)d_in[11];
  const float* Wg2 = (const float*)d_in[12];
  const float* bg2 = (const float*)d_in[13];
  const float* Wef1 = (const float*)d_in[14];
  const float* bef1 = (const float*)d_in[15];
  const float* Wef2 = (const float*)d_in[16];
  const float* bef2 = (const float*)d_in[17];
  const float* Wih_n = (const float*)d_in[18];
  const float* Whh_n = (const float*)d_in[19];
  const float* b_n   = (const float*)d_in[20];
  const float* Wih_e = (const float*)d_in[21];
  const float* Whh_e = (const float*)d_in[22];
  const float* b_e   = (const float*)d_in[23];
  const float* Wc1 = (const float*)d_in[24];
  const float* bc1 = (const float*)d_in[25];
  const float* Wc2 = (const float*)d_in[26];
  const float* bc2 = (const float*)d_in[27];

  // workspace: xn/hn [128][512][128] f32 (33.5MB), en/he [512][512][128] f32 (134MB)
  float* xn = (float*)d_ws;
  float* en = xn + (size_t)128 * T_ * HN_;
  float* out = (float*)d_out;

  node_mlp_kernel<<<32*512, 128, 0, stream>>>(x_seq, Wn1, bn1, Wn2, bn2,
                                              Wg1, bg1, Wg2, bg2, xn);
  edge_mlp_kernel<<<32*512, 128, 0, stream>>>(ea, We1, be1, We2, be2,
                                              Wef1, bef1, Wef2, bef2, en);
  lstm_mfma_kernel<<<80, 512, 0, stream>>>(Wih_n, Whh_n, b_n,
                                           Wih_e, Whh_e, b_e, xn, en);
  classifier_mfma_kernel<<<256, 512, 0, stream>>>(xn, en, Wc1, bc1, Wc2, bc2, out);
}

// Round 5
// 776.315 us; speedup vs baseline: 5.5739x; 1.7191x over previous
//
#include <hip/hip_runtime.h>
#include <cstdint>

// Problem constants (B,T,N,E)=(32,512,4,16), NI=16, EI=8, HN=HE=128, MH=256, C=8
constexpr int T_  = 512;
constexpr int HN_ = 128;

#define DEVI __device__ __forceinline__

typedef __bf16 bf16x8 __attribute__((ext_vector_type(8)));
typedef __bf16 bf16x4 __attribute__((ext_vector_type(4)));
typedef __bf16 bf16x2 __attribute__((ext_vector_type(2)));
typedef float  f32x4  __attribute__((ext_vector_type(4)));

DEVI float sigf(float x) { return __builtin_amdgcn_rcpf(1.f + __expf(-x)); }
DEVI float tanh_fast(float x) {
  x = fminf(fmaxf(x, -15.f), 15.f);
  return 1.f - 2.f * __builtin_amdgcn_rcpf(1.f + __expf(2.f * x));
}

// ---- shared MFMA layer helpers (64-row tile, 128->128, wave w owns cols n)
// src: bf16 LDS pitch 136; dst: bf16 LDS pitch 136 (relu) or f32 pitch 132.
DEVI void layer128_bf(const __bf16* __restrict__ src, __bf16* __restrict__ dst,
                      bf16x8 w0, bf16x8 w1, bf16x8 w2, bf16x8 w3,
                      float bv, int lm, int lh, int n)
{
  #pragma unroll
  for (int m = 0; m < 4; ++m) {
    const __bf16* sp = &src[(m*16 + lm)*136 + lh*8];
    const bf16x8 a0 = *reinterpret_cast<const bf16x8*>(sp);
    const bf16x8 a1 = *reinterpret_cast<const bf16x8*>(sp + 32);
    const bf16x8 a2 = *reinterpret_cast<const bf16x8*>(sp + 64);
    const bf16x8 a3 = *reinterpret_cast<const bf16x8*>(sp + 96);
    f32x4 acc = { bv, bv, bv, bv };
    acc = __builtin_amdgcn_mfma_f32_16x16x32_bf16(a0, w0, acc, 0, 0, 0);
    acc = __builtin_amdgcn_mfma_f32_16x16x32_bf16(a1, w1, acc, 0, 0, 0);
    acc = __builtin_amdgcn_mfma_f32_16x16x32_bf16(a2, w2, acc, 0, 0, 0);
    acc = __builtin_amdgcn_mfma_f32_16x16x32_bf16(a3, w3, acc, 0, 0, 0);
    #pragma unroll
    for (int r = 0; r < 4; ++r)
      dst[(m*16 + lh*4 + r)*136 + n] = (__bf16)fmaxf(acc[r], 0.f);
  }
}

DEVI void layer128_f32(const __bf16* __restrict__ src, float* __restrict__ dst,
                       bf16x8 w0, bf16x8 w1, bf16x8 w2, bf16x8 w3,
                       float bv, bool relu, int lm, int lh, int n)
{
  #pragma unroll
  for (int m = 0; m < 4; ++m) {
    const __bf16* sp = &src[(m*16 + lm)*136 + lh*8];
    const bf16x8 a0 = *reinterpret_cast<const bf16x8*>(sp);
    const bf16x8 a1 = *reinterpret_cast<const bf16x8*>(sp + 32);
    const bf16x8 a2 = *reinterpret_cast<const bf16x8*>(sp + 64);
    const bf16x8 a3 = *reinterpret_cast<const bf16x8*>(sp + 96);
    f32x4 acc = { bv, bv, bv, bv };
    acc = __builtin_amdgcn_mfma_f32_16x16x32_bf16(a0, w0, acc, 0, 0, 0);
    acc = __builtin_amdgcn_mfma_f32_16x16x32_bf16(a1, w1, acc, 0, 0, 0);
    acc = __builtin_amdgcn_mfma_f32_16x16x32_bf16(a2, w2, acc, 0, 0, 0);
    acc = __builtin_amdgcn_mfma_f32_16x16x32_bf16(a3, w3, acc, 0, 0, 0);
    #pragma unroll
    for (int r = 0; r < 4; ++r)
      dst[(m*16 + lh*4 + r)*132 + n] = relu ? fmaxf(acc[r], 0.f) : acc[r];
  }
}

// ---------------- K1: node MLP + 2 graph-conv layers (MFMA) -> xn
// 512 blocks x 512 thr; group = 64 rows = 16 (b,t) x 4 nodes; 1024 groups.
__global__ __launch_bounds__(512, 4) void node_mlp_mfma_kernel(
    const float* __restrict__ x_seq,
    const float* __restrict__ Wn1, const float* __restrict__ bn1,
    const float* __restrict__ Wn2, const float* __restrict__ bn2,
    const float* __restrict__ Wg1, const float* __restrict__ bg1,
    const float* __restrict__ Wg2, const float* __restrict__ bg2,
    float* __restrict__ xn)
{
  constexpr int P1 = 40;
  __shared__ __align__(16) __bf16 A1[64 * P1];
  __shared__ __align__(16) __bf16 Ab[64 * 136];
  __shared__ __align__(16) __bf16 Bb[64 * 136];
  __shared__ __align__(16) float  Yf[64 * 132];

  const int tid = threadIdx.x;
  const int w = tid >> 6, l = tid & 63, lm = l & 15, lh = l >> 4;
  const int n = w*16 + lm;

  bf16x8 w1, w2[4], w3[4], w4[4];
  const float b1 = bn1[n], b2 = bn2[n];
  #pragma unroll
  for (int j = 0; j < 8; ++j) {
    const int k = lh*8 + j;
    w1[j] = (k < 16) ? (__bf16)Wn1[k*128 + n] : (__bf16)0.f;
  }
  #pragma unroll
  for (int kt = 0; kt < 4; ++kt)
    #pragma unroll
    for (int j = 0; j < 8; ++j) {
      const int k = kt*32 + lh*8 + j;
      w2[kt][j] = (__bf16)Wn2[k*128 + n];
      w3[kt][j] = (__bf16)Wg1[k*128 + n];
      w4[kt][j] = (__bf16)Wg2[k*128 + n];
    }

  for (int i = tid; i < 64 * P1; i += 512) A1[i] = (__bf16)0.f;

  for (int g = blockIdx.x; g < 1024; g += 512) {
    // stage 64 rows x 16 inputs (coalesced: flat = g*1024 + i)
    #pragma unroll
    for (int it = 0; it < 2; ++it) {
      const int i = tid + it*512;
      A1[(i >> 4)*P1 + (i & 15)] = (__bf16)x_seq[(size_t)g*1024 + i];
    }
    __syncthreads();
    // L1: 16 -> 128 (K=32, zero-padded)
    #pragma unroll
    for (int m = 0; m < 4; ++m) {
      const bf16x8 a = *reinterpret_cast<const bf16x8*>(&A1[(m*16+lm)*P1 + lh*8]);
      f32x4 acc = { b1, b1, b1, b1 };
      acc = __builtin_amdgcn_mfma_f32_16x16x32_bf16(a, w1, acc, 0, 0, 0);
      #pragma unroll
      for (int r = 0; r < 4; ++r)
        Ab[(m*16 + lh*4 + r)*136 + n] = (__bf16)fmaxf(acc[r], 0.f);
    }
    __syncthreads();
    layer128_bf(Ab, Bb, w2[0], w2[1], w2[2], w2[3], b2, lm, lh, n);   // L2
    __syncthreads();
    layer128_f32(Bb, Yf, w3[0], w3[1], w3[2], w3[3], 0.f, false, lm, lh, n); // G1 matmul
    __syncthreads();
    // mix1 + bg1 + relu -> Ab (bf16)
    #pragma unroll
    for (int it = 0; it < 4; ++it) {
      const int idx = tid + it*512;
      const int q = idx >> 7, d = idx & 127;
      const float y0 = Yf[(q*4+0)*132 + d], y1 = Yf[(q*4+1)*132 + d];
      const float y2 = Yf[(q*4+2)*132 + d], y3 = Yf[(q*4+3)*132 + d];
      const float s = y0 + y1 + y2 + y3;
      const float bv = bg1[d];
      Ab[(q*4+0)*136 + d] = (__bf16)fmaxf((s + y0)*0.2f + bv, 0.f);
      Ab[(q*4+1)*136 + d] = (__bf16)fmaxf((s + y1)*0.2f + bv, 0.f);
      Ab[(q*4+2)*136 + d] = (__bf16)fmaxf((s + y2)*0.2f + bv, 0.f);
      Ab[(q*4+3)*136 + d] = (__bf16)fmaxf((s + y3)*0.2f + bv, 0.f);
    }
    __syncthreads();
    layer128_f32(Ab, Yf, w4[0], w4[1], w4[2], w4[3], 0.f, false, lm, lh, n); // G2 matmul
    __syncthreads();
    // mix2 + bg2 + relu -> global (LSTM layout [(b*4+n)][t][128])
    #pragma unroll
    for (int it = 0; it < 4; ++it) {
      const int idx = tid + it*512;
      const int q = idx >> 7, d = idx & 127;
      const int bt = g*16 + q, bb = bt >> 9, tt = bt & 511;
      const float y0 = Yf[(q*4+0)*132 + d], y1 = Yf[(q*4+1)*132 + d];
      const float y2 = Yf[(q*4+2)*132 + d], y3 = Yf[(q*4+3)*132 + d];
      const float s = y0 + y1 + y2 + y3;
      const float bv = bg2[d];
      xn[((size_t)(bb*4+0)*T_ + tt)*HN_ + d] = fmaxf((s + y0)*0.2f + bv, 0.f);
      xn[((size_t)(bb*4+1)*T_ + tt)*HN_ + d] = fmaxf((s + y1)*0.2f + bv, 0.f);
      xn[((size_t)(bb*4+2)*T_ + tt)*HN_ + d] = fmaxf((s + y2)*0.2f + bv, 0.f);
      xn[((size_t)(bb*4+3)*T_ + tt)*HN_ + d] = fmaxf((s + y3)*0.2f + bv, 0.f);
    }
    __syncthreads();
  }
}

// ---------------- K2: edge MLP (4 layers, MFMA) -> en
// 512 blocks x 512 thr; group = 64 rows = 4 (b,t) x 16 edges; 4096 groups.
__global__ __launch_bounds__(512, 4) void edge_mlp_mfma_kernel(
    const float* __restrict__ ea,
    const float* __restrict__ We1, const float* __restrict__ be1,
    const float* __restrict__ We2, const float* __restrict__ be2,
    const float* __restrict__ Wef1, const float* __restrict__ bef1,
    const float* __restrict__ Wef2, const float* __restrict__ bef2,
    float* __restrict__ en)
{
  constexpr int P1 = 40;
  __shared__ __align__(16) __bf16 A1[64 * P1];
  __shared__ __align__(16) __bf16 Ab[64 * 136];
  __shared__ __align__(16) __bf16 Bb[64 * 136];
  __shared__ __align__(16) float  Of[64 * 132];

  const int tid = threadIdx.x;
  const int w = tid >> 6, l = tid & 63, lm = l & 15, lh = l >> 4;
  const int n = w*16 + lm;

  bf16x8 w1, w2[4], w3[4], w4[4];
  const float b1 = be1[n], b2 = be2[n], b3 = bef1[n], b4 = bef2[n];
  #pragma unroll
  for (int j = 0; j < 8; ++j) {
    const int k = lh*8 + j;
    w1[j] = (k < 8) ? (__bf16)We1[k*128 + n] : (__bf16)0.f;
  }
  #pragma unroll
  for (int kt = 0; kt < 4; ++kt)
    #pragma unroll
    for (int j = 0; j < 8; ++j) {
      const int k = kt*32 + lh*8 + j;
      w2[kt][j] = (__bf16)We2[k*128 + n];
      w3[kt][j] = (__bf16)Wef1[k*128 + n];
      w4[kt][j] = (__bf16)Wef2[k*128 + n];
    }

  for (int i = tid; i < 64 * P1; i += 512) A1[i] = (__bf16)0.f;

  for (int g = blockIdx.x; g < 4096; g += 512) {
    // stage 64 rows x 8 inputs (flat = g*512 + tid, fully coalesced)
    A1[(tid >> 3)*P1 + (tid & 7)] = (__bf16)ea[(size_t)g*512 + tid];
    __syncthreads();
    // L1: 8 -> 128
    #pragma unroll
    for (int m = 0; m < 4; ++m) {
      const bf16x8 a = *reinterpret_cast<const bf16x8*>(&A1[(m*16+lm)*P1 + lh*8]);
      f32x4 acc = { b1, b1, b1, b1 };
      acc = __builtin_amdgcn_mfma_f32_16x16x32_bf16(a, w1, acc, 0, 0, 0);
      #pragma unroll
      for (int r = 0; r < 4; ++r)
        Ab[(m*16 + lh*4 + r)*136 + n] = (__bf16)fmaxf(acc[r], 0.f);
    }
    __syncthreads();
    layer128_bf(Ab, Bb, w2[0], w2[1], w2[2], w2[3], b2, lm, lh, n);          // L2
    __syncthreads();
    layer128_bf(Bb, Ab, w3[0], w3[1], w3[2], w3[3], b3, lm, lh, n);          // L3
    __syncthreads();
    layer128_f32(Ab, Of, w4[0], w4[1], w4[2], w4[3], b4, true, lm, lh, n);   // L4
    __syncthreads();
    // write out 64 rows x 128 f32, coalesced float4 (LSTM layout)
    #pragma unroll
    for (int i = 0; i < 4; ++i) {
      const int fi = tid + i*512;            // 2048 float4
      const int row = fi >> 5, c4 = fi & 31;
      const int q = row >> 4, e = row & 15;
      const int bt = g*4 + q, bb = bt >> 9, tt = bt & 511;
      const float4 v = *reinterpret_cast<const float4*>(&Of[row*132 + c4*4]);
      *reinterpret_cast<float4*>(
          &en[((size_t)(bb*16+e)*T_ + tt)*HN_ + c4*4]) = v;
    }
    __syncthreads();
  }
}

// ---------------- K3: fused MFMA LSTM, swapped operands (z^T = W^T @ x/h^T)
// h written to LDS h_hist (f32), flushed to global once per 16-step chunk so
// per-step barriers carry NO outstanding VMEM (no vmcnt(0) drain per step).
__global__ __launch_bounds__(512, 1) void lstm_mfma_kernel(
    const float* __restrict__ Wih_n, const float* __restrict__ Whh_n,
    const float* __restrict__ b_n,
    const float* __restrict__ Wih_e, const float* __restrict__ Whh_e,
    const float* __restrict__ b_e,
    float* __restrict__ xn, float* __restrict__ en)
{
  constexpr int XROW = 2064;  // bf16 per seq row of x chunk (16*128 + 16 pad)
  constexpr int HROW = 144;   // bf16 per h row (128 + 16 pad)
  constexpr int SPAD = 2056;  // f32 per seq row of h_hist (16*128 + 8 pad)
  __shared__ __align__(16) __bf16 x_c[8 * XROW];
  __shared__ __align__(16) __bf16 x_zero[XROW];
  __shared__ __align__(16) __bf16 h_bf[8 * HROW];
  __shared__ __align__(16) __bf16 h_zero[HROW];
  __shared__ __align__(16) float  h_hist[8 * SPAD];

  const bool is_node = (int)blockIdx.x < 16;
  const int  bidx    = is_node ? blockIdx.x : ((int)blockIdx.x - 16);
  const float* __restrict__ Wih  = is_node ? Wih_n : Wih_e;
  const float* __restrict__ Whh  = is_node ? Whh_n : Whh_e;
  const float* __restrict__ bias = is_node ? b_n   : b_e;
  float* __restrict__ xh = (is_node ? xn : en) + (size_t)bidx * 8 * (T_ * HN_);

  const int tid = threadIdx.x;
  const int w   = tid >> 6;       // wave 0..7 -> dims [16w,16w+16)
  const int l   = tid & 63;
  const int lm  = l & 15;         // A row (gate) / B col (seq)
  const int lh  = l >> 4;

  // A-operand fragments: A[m][k] = W[k][gate], m=lm, k=kt*32+lh*8+j
  bf16x8 wih_f[4][4], whh_f[4][4];
  f32x4  bias_v[4];
  #pragma unroll
  for (int nt = 0; nt < 4; ++nt) {
    const int g0 = nt*128 + w*16;
    bias_v[nt] = *reinterpret_cast<const f32x4*>(&bias[g0 + lh*4]);
    #pragma unroll
    for (int kt = 0; kt < 4; ++kt) {
      #pragma unroll
      for (int j = 0; j < 8; ++j) {
        const int k = kt*32 + lh*8 + j;
        wih_f[nt][kt][j] = (__bf16)Wih[k*512 + g0 + lm];
        whh_f[nt][kt][j] = (__bf16)Whh[k*512 + g0 + lm];
      }
    }
  }

  for (int i = tid; i < XROW; i += 512) x_zero[i] = (__bf16)0.f;
  for (int i = tid; i < 8 * HROW; i += 512) h_bf[i] = (__bf16)0.f;
  if (tid < HROW) h_zero[tid] = (__bf16)0.f;

  const __bf16* __restrict__ xrow = (lm < 8) ? &x_c[lm * XROW] : x_zero;
  const __bf16* __restrict__ hrow = (lm < 8) ? &h_bf[lm * HROW] : h_zero;

  const bool hi_half = lm >= 8;
  const int  s  = lm & 7;
  const int  dl = w*16 + lh*4 + (hi_half ? 2 : 0);
  float c0 = 0.f, c1 = 0.f;

  for (int t = 0; t < T_; ++t) {
    if ((t & 15) == 0) {
      if (t) {
        // bulk flush h for steps t-16..t-1 (reads ordered by last step's barrier)
        #pragma unroll
        for (int i = 0; i < 8; ++i) {
          const int fi = tid + i*512;
          const int sq = fi >> 9, rem = fi & 511;
          const int tl = rem >> 5, k = (rem & 31)*4;
          const float4 v = *reinterpret_cast<const float4*>(
              &h_hist[sq*SPAD + tl*128 + k]);
          *reinterpret_cast<float4*>(
              &xh[(size_t)sq*(T_*HN_) + (size_t)(t-16+tl)*HN_ + k]) = v;
        }
      }
      // stage x chunk t..t+15 (8 seq x 16 t x 128 k, f32 -> bf16)
      #pragma unroll
      for (int i = 0; i < 8; ++i) {
        const int f4  = (tid + i*512) * 4;
        const int sq  = f4 >> 11;
        const int rem = f4 & 2047;
        const float4 v = *reinterpret_cast<const float4*>(
            &xh[(size_t)sq*(T_*HN_) + (size_t)t*HN_ + rem]);
        bf16x4 pk;
        pk[0] = (__bf16)v.x; pk[1] = (__bf16)v.y;
        pk[2] = (__bf16)v.z; pk[3] = (__bf16)v.w;
        *reinterpret_cast<bf16x4*>(&x_c[sq*XROW + rem]) = pk;
      }
      __syncthreads();
    }
    const int tl = t & 15;

    bf16x8 bx[4], bh[4];
    #pragma unroll
    for (int kt = 0; kt < 4; ++kt) {
      bx[kt] = *reinterpret_cast<const bf16x8*>(&xrow[tl*128 + kt*32 + lh*8]);
      bh[kt] = *reinterpret_cast<const bf16x8*>(&hrow[kt*32 + lh*8]);
    }

    f32x4 accs[4];
    #pragma unroll
    for (int nt = 0; nt < 4; ++nt) {
      f32x4 acc = bias_v[nt];
      #pragma unroll
      for (int kt = 0; kt < 4; ++kt) {
        acc = __builtin_amdgcn_mfma_f32_16x16x32_bf16(wih_f[nt][kt], bx[kt], acc, 0, 0, 0);
        acc = __builtin_amdgcn_mfma_f32_16x16x32_bf16(whh_f[nt][kt], bh[kt], acc, 0, 0, 0);
      }
      accs[nt] = acc;
    }

    float z0[4], z1[4];
    #pragma unroll
    for (int nt = 0; nt < 4; ++nt) {
      const float a2 = __shfl_up(accs[nt][2], 8u, 16);
      const float a3 = __shfl_up(accs[nt][3], 8u, 16);
      z0[nt] = hi_half ? a2 : accs[nt][0];
      z1[nt] = hi_half ? a3 : accs[nt][1];
    }
    c0 = sigf(z0[1]) * c0 + sigf(z0[0]) * tanh_fast(z0[2]);
    const float h0 = sigf(z0[3]) * tanh_fast(c0);
    c1 = sigf(z1[1]) * c1 + sigf(z1[0]) * tanh_fast(z1[2]);
    const float h1 = sigf(z1[3]) * tanh_fast(c1);

    bf16x2 hb; hb[0] = (__bf16)h0; hb[1] = (__bf16)h1;
    *reinterpret_cast<bf16x2*>(&h_bf[s*HROW + dl]) = hb;
    float2 ho; ho.x = h0; ho.y = h1;
    *reinterpret_cast<float2*>(&h_hist[s*SPAD + tl*128 + dl]) = ho;  // LDS only
    __syncthreads();
  }
  // final flush (steps 496..511)
  #pragma unroll
  for (int i = 0; i < 8; ++i) {
    const int fi = tid + i*512;
    const int sq = fi >> 9, rem = fi & 511;
    const int tl = rem >> 5, k = (rem & 31)*4;
    const float4 v = *reinterpret_cast<const float4*>(
        &h_hist[sq*SPAD + tl*128 + k]);
    *reinterpret_cast<float4*>(
        &xh[(size_t)sq*(T_*HN_) + (size_t)(T_-16+tl)*HN_ + k]) = v;
  }
}

// ---------------- K4: MFMA gather + classifier (384 -> 256 -> 8)
__global__ __launch_bounds__(512, 1) void classifier_mfma_kernel(
    const float* __restrict__ hn, const float* __restrict__ he,
    const float* __restrict__ Wc1, const float* __restrict__ bc1,
    const float* __restrict__ Wc2, const float* __restrict__ bc2,
    float* __restrict__ out)
{
  constexpr int HP = 136;
  constexpr int DP = 264;
  __shared__ __align__(16) __bf16 hn_l[32 * HP];
  __shared__ __align__(16) __bf16 he_l[128 * HP];
  __shared__ __align__(16) __bf16 hid_l[128 * DP];

  const int tid = threadIdx.x;
  const int w   = tid >> 6;
  const int l   = tid & 63;
  const int lm  = l & 15;
  const int lh  = l >> 4;

  bf16x8 wb[2][12];
  float  bcol[2];
  #pragma unroll
  for (int jt = 0; jt < 2; ++jt) {
    const int j = w*32 + jt*16 + lm;
    bcol[jt] = bc1[j];
    #pragma unroll
    for (int kt = 0; kt < 12; ++kt)
      #pragma unroll
      for (int i = 0; i < 8; ++i)
        wb[jt][kt][i] = (__bf16)Wc1[(kt*32 + lh*8 + i)*256 + j];
  }
  bf16x8 wc2f[8];
  const float bc2v = (lm < 8) ? bc2[lm] : 0.f;
  #pragma unroll
  for (int kt = 0; kt < 8; ++kt)
    #pragma unroll
    for (int i = 0; i < 8; ++i)
      wc2f[kt][i] = (lm < 8) ? (__bf16)Wc2[(kt*32 + lh*8 + i)*8 + lm] : (__bf16)0.f;

  for (int g = blockIdx.x; g < 2048; g += 256) {
    const int b  = g >> 6;
    const int t0 = (g & 63) * 8;

    for (int i = tid; i < 4096; i += 512) {
      const int f4 = i * 4;
      const int e  = f4 >> 10;
      const int rem = f4 & 1023;
      const int tt = rem >> 7;
      const int k  = rem & 127;
      const float4 v = *reinterpret_cast<const float4*>(
          &he[((size_t)(b*16+e)*T_ + t0 + tt)*HN_ + k]);
      __bf16* p = &he_l[(tt*16 + e)*HP + k];
      p[0]=(__bf16)v.x; p[1]=(__bf16)v.y; p[2]=(__bf16)v.z; p[3]=(__bf16)v.w;
    }
    for (int i = tid; i < 1024; i += 512) {
      const int f4 = i * 4;
      const int n  = f4 >> 10;
      const int rem = f4 & 1023;
      const int tt = rem >> 7;
      const int k  = rem & 127;
      const float4 v = *reinterpret_cast<const float4*>(
          &hn[((size_t)(b*4+n)*T_ + t0 + tt)*HN_ + k]);
      __bf16* p = &hn_l[(tt*4 + n)*HP + k];
      p[0]=(__bf16)v.x; p[1]=(__bf16)v.y; p[2]=(__bf16)v.z; p[3]=(__bf16)v.w;
    }
    __syncthreads();

    for (int tt = 0; tt < 8; ++tt) {
      bf16x8 af[12];
      #pragma unroll
      for (int kt = 0; kt < 4; ++kt)
        af[kt] = *reinterpret_cast<const bf16x8*>(
            &hn_l[(tt*4 + (lm>>2))*HP + kt*32 + lh*8]);
      #pragma unroll
      for (int kt = 0; kt < 4; ++kt)
        af[4+kt] = *reinterpret_cast<const bf16x8*>(
            &hn_l[(tt*4 + (lm&3))*HP + kt*32 + lh*8]);
      #pragma unroll
      for (int kt = 0; kt < 4; ++kt)
        af[8+kt] = *reinterpret_cast<const bf16x8*>(
            &he_l[(tt*16 + lm)*HP + kt*32 + lh*8]);
      #pragma unroll
      for (int jt = 0; jt < 2; ++jt) {
        f32x4 acc = { bcol[jt], bcol[jt], bcol[jt], bcol[jt] };
        #pragma unroll
        for (int kt = 0; kt < 12; ++kt)
          acc = __builtin_amdgcn_mfma_f32_16x16x32_bf16(af[kt], wb[jt][kt], acc, 0, 0, 0);
        #pragma unroll
        for (int r = 0; r < 4; ++r)
          hid_l[(tt*16 + lh*4 + r)*DP + (w*2 + jt)*16 + lm] = (__bf16)fmaxf(acc[r], 0.f);
      }
    }
    __syncthreads();

    {
      const int tt = w;
      f32x4 acc = { bc2v, bc2v, bc2v, bc2v };
      #pragma unroll
      for (int kt = 0; kt < 8; ++kt) {
        const bf16x8 a = *reinterpret_cast<const bf16x8*>(
            &hid_l[(tt*16 + lm)*DP + kt*32 + lh*8]);
        acc = __builtin_amdgcn_mfma_f32_16x16x32_bf16(a, wc2f[kt], acc, 0, 0, 0);
      }
      if (lm < 8) {
        const size_t bt = (size_t)b*T_ + t0 + tt;
        #pragma unroll
        for (int r = 0; r < 4; ++r)
          out[(bt*16 + lh*4 + r)*8 + lm] = acc[r];
      }
    }
    __syncthreads();
  }
}

extern "C" void kernel_launch(void* const* d_in, const int* in_sizes, int n_in,
                              void* d_out, int out_size, void* d_ws, size_t ws_size,
                              hipStream_t stream) {
  (void)in_sizes; (void)n_in; (void)out_size; (void)ws_size;
  const float* x_seq = (const float*)d_in[0];
  const float* ea    = (const float*)d_in[1];
  const float* Wn1 = (const float*)d_in[2];
  const float* bn1 = (const float*)d_in[3];
  const float* Wn2 = (const float*)d_in[4];
  const float* bn2 = (const float*)d_in[5];
  const float* We1 = (const float*)d_in[6];
  const float* be1 = (const float*)d_in[7];
  const float* We2 = (const float*)d_in[8];
  const float* be2 = (const float*)d_in[9];
  const float* Wg1 = (const float*)d_in[10];
  const float* bg1 = (const float*)d_in[11];
  const float* Wg2 = (const float*)d_in[12];
  const float* bg2 = (const float*)d_in[13];
  const float* Wef1 = (const float*)d_in[14];
  const float* bef1 = (const float*)d_in[15];
  const float* Wef2 = (const float*)d_in[16];
  const float* bef2 = (const float*)d_in[17];
  const float* Wih_n = (const float*)d_in[18];
  const float* Whh_n = (const float*)d_in[19];
  const float* b_n   = (const float*)d_in[20];
  const float* Wih_e = (const float*)d_in[21];
  const float* Whh_e = (const float*)d_in[22];
  const float* b_e   = (const float*)d_in[23];
  const float* Wc1 = (const float*)d_in[24];
  const float* bc1 = (const float*)d_in[25];
  const float* Wc2 = (const float*)d_in[26];
  const float* bc2 = (const float*)d_in[27];

  // workspace: xn/hn [128][512][128] f32 (33.5MB), en/he [512][512][128] f32 (134MB)
  float* xn = (float*)d_ws;
  float* en = xn + (size_t)128 * T_ * HN_;
  float* out = (float*)d_out;

  node_mlp_mfma_kernel<<<512, 512, 0, stream>>>(x_seq, Wn1, bn1, Wn2, bn2,
                                                Wg1, bg1, Wg2, bg2, xn);
  edge_mlp_mfma_kernel<<<512, 512, 0, stream>>>(ea, We1, be1, We2, be2,
                                                Wef1, bef1, Wef2, bef2, en);
  lstm_mfma_kernel<<<80, 512, 0, stream>>>(Wih_n, Whh_n, b_n,
                                           Wih_e, Whh_e, b_e, xn, en);
  classifier_mfma_kernel<<<256, 512, 0, stream>>>(xn, en, Wc1, bc1, Wc2, bc2, out);
}